// Round 1
// 1237.891 us; speedup vs baseline: 1.0285x; 1.0285x over previous
//
#include <hip/hip_runtime.h>

// Problem constants
constexpr int Bsz = 2, Tsz = 512, Csz = 1024, Hsz = 16, Dsz = 64, CSz = 64;
constexpr int NCHUNK = 8, OW = 8;

// Polar Express quintic coefficients (first NS_STEPS=5 rows)
__constant__ float PE_A[5] = {8.28721201814563f, 4.107059111542203f, 3.9486908534822946f,
                              3.3184196573706015f, 2.300652019954817f};
__constant__ float PE_B[5] = {-23.595886519098837f, -2.9478499167379106f, -2.908902115962949f,
                              -2.488488024314874f, -1.6689039845747493f};
__constant__ float PE_C[5] = {17.300387312530933f, 0.5448431082926601f, 0.5518191394370137f,
                              0.51004894012372f, 0.4188073119525673f};

typedef __attribute__((ext_vector_type(8))) _Float16 half8;
typedef __attribute__((ext_vector_type(4))) _Float16 half4;
typedef __attribute__((ext_vector_type(16))) float f32x16;

// ---------------------------------------------------------------------------
// Generic tiled GEMM:  O[m][n] = sum_k A[m][k] * W[n][k]   (i.e. A @ W.T)
// ---------------------------------------------------------------------------
__global__ __launch_bounds__(256) void gemm_nt(const float* __restrict__ A,
                                               const float* __restrict__ W,
                                               float* __restrict__ O,
                                               int M, int N, int K) {
  __shared__ float As[16][68];
  __shared__ float Ws[16][68];
  const int tid = threadIdx.x;
  const int m0 = blockIdx.x * 64, n0 = blockIdx.y * 64;
  const int tm = tid & 15, tn = tid >> 4;
  const int lr = tid >> 2, lk = (tid & 3) << 2;
  float acc[4][4] = {};
  for (int k0 = 0; k0 < K; k0 += 16) {
    float4 av = *(const float4*)(A + (size_t)(m0 + lr) * K + k0 + lk);
    float4 wv = *(const float4*)(W + (size_t)(n0 + lr) * K + k0 + lk);
    __syncthreads();
    As[lk + 0][lr] = av.x; As[lk + 1][lr] = av.y; As[lk + 2][lr] = av.z; As[lk + 3][lr] = av.w;
    Ws[lk + 0][lr] = wv.x; Ws[lk + 1][lr] = wv.y; Ws[lk + 2][lr] = wv.z; Ws[lk + 3][lr] = wv.w;
    __syncthreads();
#pragma unroll
    for (int k = 0; k < 16; ++k) {
      float4 a4 = *(const float4*)&As[k][tm << 2];
      float4 w4 = *(const float4*)&Ws[k][tn << 2];
      float a_[4] = {a4.x, a4.y, a4.z, a4.w};
      float w_[4] = {w4.x, w4.y, w4.z, w4.w};
#pragma unroll
      for (int i = 0; i < 4; ++i)
#pragma unroll
        for (int j = 0; j < 4; ++j) acc[i][j] += a_[i] * w_[j];
    }
  }
#pragma unroll
  for (int i = 0; i < 4; ++i) {
    float4 o = {acc[i][0], acc[i][1], acc[i][2], acc[i][3]};
    *(float4*)(O + (size_t)(m0 + (tm << 2) + i) * N + n0 + (tn << 2)) = o;
  }
}

// ---------------------------------------------------------------------------
// Gates
// ---------------------------------------------------------------------------
__global__ __launch_bounds__(64) void gates_kernel(const float* __restrict__ x,
                                                   const float* __restrict__ Wa,
                                                   const float* __restrict__ We,
                                                   const float* __restrict__ Wt,
                                                   const float* __restrict__ Wg,
                                                   float* __restrict__ ga, float* __restrict__ ge,
                                                   float* __restrict__ gt, float* __restrict__ gg) {
  __shared__ float xs[Csz];
  const int bt = blockIdx.x;
  const int tid = threadIdx.x;
  const float* xr = x + (size_t)bt * Csz;
  for (int i = tid * 4; i < Csz; i += 64 * 4) *(float4*)&xs[i] = *(const float4*)&xr[i];
  __syncthreads();
  const int gsel = tid >> 4, h = tid & 15;
  const float* Wrow = (gsel == 0 ? Wa : gsel == 1 ? We : gsel == 2 ? Wt : Wg) + (size_t)h * Csz;
  float acc = 0.f;
  for (int i = 0; i < Csz; i += 4) {
    float4 w4 = *(const float4*)&Wrow[i];
    acc += xs[i] * w4.x + xs[i + 1] * w4.y + xs[i + 2] * w4.z + xs[i + 3] * w4.w;
  }
  float s = 1.f / (1.f + expf(-acc));
  float* outp = (gsel == 0 ? ga : gsel == 1 ? ge : gsel == 2 ? gt : gg);
  outp[(size_t)bt * Hsz + h] = s;
}

// ---------------------------------------------------------------------------
// Causal depthwise conv (K=4) + optional rms_norm/poly
// ---------------------------------------------------------------------------
__global__ __launch_bounds__(256) void conv_kernel(const float* __restrict__ lin,
                                                   const float* __restrict__ w,
                                                   const float* __restrict__ bias,
                                                   float* __restrict__ out, int do_norm) {
  const int bt = blockIdx.x;
  const int b = bt >> 9, t = bt & 511;
  const int tid = threadIdx.x;
  const int c0 = tid << 2;
  float4 bv = *(const float4*)&bias[c0];
  float v0 = bv.x, v1 = bv.y, v2 = bv.z, v3 = bv.w;
  float4 w0 = *(const float4*)&w[(c0 + 0) * 4];
  float4 w1 = *(const float4*)&w[(c0 + 1) * 4];
  float4 w2 = *(const float4*)&w[(c0 + 2) * 4];
  float4 w3 = *(const float4*)&w[(c0 + 3) * 4];
  const float* base = lin + (size_t)b * Tsz * Csz + c0;
#pragma unroll
  for (int j = 0; j < 4; ++j) {
    int tt = t - 3 + j;
    if (tt < 0) continue;
    float4 xv = *(const float4*)(base + (size_t)tt * Csz);
    v0 += xv.x * (&w0.x)[j];
    v1 += xv.y * (&w1.x)[j];
    v2 += xv.z * (&w2.x)[j];
    v3 += xv.w * (&w3.x)[j];
  }
  if (do_norm) {
    float ss = v0 * v0 + v1 * v1 + v2 * v2 + v3 * v3;
    ss += __shfl_xor(ss, 1, 16);
    ss += __shfl_xor(ss, 2, 16);
    ss += __shfl_xor(ss, 4, 16);
    ss += __shfl_xor(ss, 8, 16);
    float scl = rsqrtf(ss * (1.f / 64.f) + 1e-6f);
    v0 *= scl; v1 *= scl; v2 *= scl; v3 *= scl;
    v0 += 0.5f * v0 * v0; v1 += 0.5f * v1 * v1; v2 += 0.5f * v2 * v2; v3 += 0.5f * v3 * v3;
  }
  float4 o = {v0, v1, v2, v3};
  *(float4*)(out + (size_t)bt * Csz + c0) = o;
}

// ---------------------------------------------------------------------------
// rms_norm for y
// ---------------------------------------------------------------------------
__global__ __launch_bounds__(256) void rms_kernel(const float* __restrict__ in,
                                                  float* __restrict__ out) {
  const int bt = blockIdx.x;
  const int tid = threadIdx.x;
  const int c0 = tid << 2;
  float4 xv = *(const float4*)(in + (size_t)bt * Csz + c0);
  float ss = xv.x * xv.x + xv.y * xv.y + xv.z * xv.z + xv.w * xv.w;
  ss += __shfl_xor(ss, 1, 16);
  ss += __shfl_xor(ss, 2, 16);
  ss += __shfl_xor(ss, 4, 16);
  ss += __shfl_xor(ss, 8, 16);
  float scl = rsqrtf(ss * (1.f / 64.f) + 1e-6f);
  float4 o = {xv.x * scl, xv.y * scl, xv.z * scl, xv.w * scl};
  *(float4*)(out + (size_t)bt * Csz + c0) = o;
}

// ---------------------------------------------------------------------------
// B1+B2 fused: err = M k - v  (for this block's 4 v-rows), then
// omega window + momentum scan. Thread per (v,k) element of S.
// ---------------------------------------------------------------------------
__global__ __launch_bounds__(256) void mom_scan_kernel(const float* __restrict__ Mst,
                                                       const float* __restrict__ kp,
                                                       const float* __restrict__ vp,
                                                       const float* __restrict__ geta,
                                                       const float* __restrict__ gtheta,
                                                       const float* __restrict__ ggamma,
                                                       float* __restrict__ Sst,
                                                       float* __restrict__ chunkS, int ci) {
  __shared__ float Ml[4 * Dsz];     // 4 M-rows of this block
  __shared__ float errl[256];       // [t][vloc]
  __shared__ float kkl[CSz * Dsz];  // [t][k]
  __shared__ float gl[CSz], el[CSz], tl[CSz];
  const int blk = blockIdx.x;
  const int bh = blk >> 4, eb = blk & 15;
  const int b = bh >> 4, h = bh & 15;
  const int tid = threadIdx.x;
  Ml[tid & 255] = Mst[(size_t)bh * 4096 + eb * 4 * 64 + tid];
#pragma unroll
  for (int i = 0; i < 16; ++i) {
    int idx = i * 256 + tid;
    int t = idx >> 6, k = idx & 63;
    kkl[idx] = kp[(((size_t)b * Tsz + ci * CSz + t) * Hsz + h) * Dsz + k];
  }
  if (tid < CSz) {
    size_t gi = ((size_t)b * Tsz + ci * CSz + tid) * Hsz + h;
    gl[tid] = ggamma[gi];
    el[tid] = geta[gi];
    tl[tid] = gtheta[gi];
  }
  __syncthreads();
  {
    const int tt = tid >> 2, vl = tid & 3;
    float acc = 0.f;
#pragma unroll 8
    for (int k = 0; k < Dsz; ++k) acc += Ml[vl * 64 + k] * kkl[tt * 64 + k];
    float vv = vp[(((size_t)b * Tsz + ci * CSz + tt) * Hsz + h) * Dsz + eb * 4 + vl];
    errl[tt * 4 + vl] = acc - vv;
  }
  __syncthreads();
  const int e = eb * 256 + tid;
  const int vloc = tid >> 6;
  const int k = tid & 63;
  float S = Sst[(size_t)bh * 4096 + e];
  float ring[OW];
  float wsum = 0.f;
  float* outp = chunkS + (size_t)bh * CSz * 4096 + e;
#pragma unroll
  for (int t = 0; t < CSz; ++t) {
    float u = 2.f * errl[t * 4 + vloc] * kkl[t * 64 + k];
    float val = gl[t] * u;
    wsum += val;
    if (t >= OW) wsum -= ring[t & (OW - 1)];
    ring[t & (OW - 1)] = val;
    S = tl[t] * S - el[t] * wsum;
    outp[(size_t)t * 4096] = S;
  }
  Sst[(size_t)bh * 4096 + e] = S;
}

// ---------------------------------------------------------------------------
// B3: Polar Express via scaled split-f16 MFMA, re-associated dataflow:
//   A = X X^T ; W = A X ; U = A W ; X' = a X + b W + c U
// One 256-thread block (4 waves) per 64x64 matrix; each wave owns one 32x32
// output tile. 3 LDS plane-pairs only (X rows / X^T / A), W^T ping-pongs into
// the dead X plane; stage-3's A-operand fragments are reused from registers.
// All planes: pitch 64 f16 (128 B rows) with XOR swizzle colByte^=(row&7)<<4
// -> conflict-free b128 fragment reads. 48 KiB LDS -> 3 blocks/CU.
// fp32 v ~= hi + (lo/2048): products hh -> accH, h*lo + lo*h -> accL.
// ---------------------------------------------------------------------------
__device__ __forceinline__ void split_f16(float v, _Float16& hi, _Float16& lo) {
  _Float16 h = (_Float16)v;                 // RN
  float r = v - (float)h;                   // exact residual
  hi = h;
  lo = (_Float16)(r * 2048.0f);             // RN, scaled into normal range
}

// fragment for v_mfma_f32_32x32x16_f16: lane -> m/n = lane&31, k = 8*(lane>>5)+j
__device__ __forceinline__ half8 ldfrag(const _Float16* P, int rowbase, int ks, int lane) {
  int row = rowbase + (lane & 31);
  int colByte = (ks << 5) + ((lane >> 5) << 4);
  colByte ^= (row & 7) << 4;  // bank swizzle
  return *(const half8*)((const char*)P + (row << 7) + colByte);
}

#define MFMA2(accH, accL, ah, al, bh, bl)                                     \
  accH = __builtin_amdgcn_mfma_f32_32x32x16_f16(ah, bh, accH, 0, 0, 0);       \
  accL = __builtin_amdgcn_mfma_f32_32x32x16_f16(ah, bl, accL, 0, 0, 0);       \
  accL = __builtin_amdgcn_mfma_f32_32x32x16_f16(al, bh, accL, 0, 0, 0);

// Write this wave's 16 C-values TRANSPOSED: plane[col][row] = D[row][col].
// 4+4 swizzled ds_write_b64: plane row = nb+ccol, cols mb+crow+8g+j.
__device__ __forceinline__ void store_sym_t(_Float16* Ph, _Float16* Pl,
                                            const _Float16* hs, const _Float16* ls,
                                            int mb, int nb, int crow, int ccol) {
  const int base = (nb + ccol) << 7;
  const int sw = ((nb + ccol) & 7) << 4;
  const int c2 = crow << 1;  // 0 or 8 bytes within 16B slot
#pragma unroll
  for (int g = 0; g < 4; ++g) {
    half4 hv, lv;
#pragma unroll
    for (int j = 0; j < 4; ++j) { hv[j] = hs[g * 4 + j]; lv[j] = ls[g * 4 + j]; }
    int cb = (((mb + 8 * g) << 1) ^ sw) + c2;
    *(half4*)((char*)Ph + base + cb) = hv;
    *(half4*)((char*)Pl + base + cb) = lv;
  }
}

// Write this wave's 16 C-values in row layout: plane[row][col] = D[row][col].
__device__ __forceinline__ void store_rows(_Float16* Ph, _Float16* Pl,
                                           const _Float16* hs, const _Float16* ls,
                                           int mb, int nb, int crow, int ccol) {
#pragma unroll
  for (int r = 0; r < 16; ++r) {
    int rr = mb + crow + (r & 3) + ((r >> 2) << 3);
    int cb = ((nb + ccol) << 1) ^ ((rr & 7) << 4);
    *(_Float16*)((char*)Ph + (rr << 7) + cb) = hs[r];
    *(_Float16*)((char*)Pl + (rr << 7) + cb) = ls[r];
  }
}

__global__ __launch_bounds__(256, 3) void pe_mfma_kernel(float* __restrict__ chunkS) {
  __shared__ __attribute__((aligned(16))) _Float16 PL[6][4096];
  __shared__ float red[4];
  const int tid = threadIdx.x;
  const int lane = tid & 63;
  const int wv = tid >> 6;
  float* G = chunkS + (size_t)blockIdx.x * 4096;
  constexpr float INV_S = 1.0f / 2048.0f;

  const int mb = (wv >> 1) << 5;        // tile row base
  const int nb = (wv & 1) << 5;         // tile col base
  const int crow = ((lane >> 5) << 2);  // C-frag: row = mb+crow+(r&3)+8*(r>>2)
  const int ccol = lane & 31;           // C-frag: col = nb+ccol

  // ---- load in C-frag pattern + Frobenius normalize ----
  float Xval[16];
  float ss = 0.f;
#pragma unroll
  for (int r = 0; r < 16; ++r) {
    int rr = mb + crow + (r & 3) + ((r >> 2) << 3);
    float xv = G[rr * 64 + nb + ccol];
    Xval[r] = xv;
    ss += xv * xv;
  }
#pragma unroll
  for (int off = 32; off; off >>= 1) ss += __shfl_xor(ss, off, 64);
  if (lane == 0) red[wv] = ss;
  __syncthreads();
  float tot = red[0] + red[1] + red[2] + red[3];
  float scale = 1.f / ((sqrtf(tot) + 1e-7f) * 1.01f);

  _Float16* PXh = PL[0]; _Float16* PXl = PL[1];  // X rows (later: W^T)
  _Float16* PTh = PL[2]; _Float16* PTl = PL[3];  // X^T (fixed role)
  _Float16* PAh = PL[4]; _Float16* PAl = PL[5];  // A (later: X' rows)

  {
    _Float16 hs[16], ls[16];
#pragma unroll
    for (int r = 0; r < 16; ++r) {
      Xval[r] *= scale;
      split_f16(Xval[r], hs[r], ls[r]);
    }
    store_rows(PXh, PXl, hs, ls, mb, nb, crow, ccol);
    store_sym_t(PTh, PTl, hs, ls, mb, nb, crow, ccol);
  }

  for (int it = 0; it < 5; ++it) {
    const float ca = PE_A[it], cb = PE_B[it], cc = PE_C[it];
    __syncthreads();  // B_a: X rows (PX) + X^T (PT) stores visible; prev W^T reads drained
    // ---- stage 1: A = X X^T (both operands are row-fragments of X) ----
    f32x16 accH, accL;
#pragma unroll
    for (int r = 0; r < 16; ++r) { accH[r] = 0.f; accL[r] = 0.f; }
#pragma unroll
    for (int ks = 0; ks < 4; ++ks) {
      half8 ah = ldfrag(PXh, mb, ks, lane), al = ldfrag(PXl, mb, ks, lane);
      half8 bh = ldfrag(PXh, nb, ks, lane), bl = ldfrag(PXl, nb, ks, lane);
      MFMA2(accH, accL, ah, al, bh, bl);
    }
    {
      _Float16 hs[16], ls[16];
#pragma unroll
      for (int r = 0; r < 16; ++r) {
        float av = accH[r] + accL[r] * INV_S;
        split_f16(av, hs[r], ls[r]);
      }
      store_sym_t(PAh, PAl, hs, ls, mb, nb, crow, ccol);  // A (symmetric)
    }
    __syncthreads();  // B_b: A ready; all stage-1 X reads drained -> PX reusable
    // ---- stage 2: W = A X (A-op rows of A -> kept in regs; B-op rows of X^T) ----
    half8 fah[4], fal[4];
    f32x16 acWH, acWL;
#pragma unroll
    for (int r = 0; r < 16; ++r) { acWH[r] = 0.f; acWL[r] = 0.f; }
#pragma unroll
    for (int ks = 0; ks < 4; ++ks) {
      fah[ks] = ldfrag(PAh, mb, ks, lane);
      fal[ks] = ldfrag(PAl, mb, ks, lane);
      half8 bh = ldfrag(PTh, nb, ks, lane), bl = ldfrag(PTl, nb, ks, lane);
      MFMA2(acWH, acWL, fah[ks], fal[ks], bh, bl);
    }
    float Wval[16];
    {
      _Float16 hs[16], ls[16];
#pragma unroll
      for (int r = 0; r < 16; ++r) {
        Wval[r] = acWH[r] + acWL[r] * INV_S;
        split_f16(Wval[r], hs[r], ls[r]);
      }
      store_sym_t(PXh, PXl, hs, ls, mb, nb, crow, ccol);  // W^T into dead X plane
    }
    __syncthreads();  // B_c: W^T ready; stage-2 PT/PA reads drained
    // ---- stage 3: U = A W (A-op from regs, zero LDS reads; B-op rows of W^T) ----
    f32x16 acUH, acUL;
#pragma unroll
    for (int r = 0; r < 16; ++r) { acUH[r] = 0.f; acUL[r] = 0.f; }
#pragma unroll
    for (int ks = 0; ks < 4; ++ks) {
      half8 bh = ldfrag(PXh, nb, ks, lane), bl = ldfrag(PXl, nb, ks, lane);
      MFMA2(acUH, acUL, fah[ks], fal[ks], bh, bl);
    }
    if (it < 4) {
      _Float16 hs[16], ls[16];
#pragma unroll
      for (int r = 0; r < 16; ++r) {
        float xn = ca * Xval[r] + cb * Wval[r] + cc * (acUH[r] + acUL[r] * INV_S);
        Xval[r] = xn;
        split_f16(xn, hs[r], ls[r]);
      }
      store_rows(PAh, PAl, hs, ls, mb, nb, crow, ccol);    // X' rows -> PA
      store_sym_t(PTh, PTl, hs, ls, mb, nb, crow, ccol);   // X'^T -> PT
      // role swap: PX <-> PA (new X rows live in PA)
      _Float16* t;
      t = PXh; PXh = PAh; PAh = t;
      t = PXl; PXl = PAl; PAl = t;
    } else {
      // ---- final store (fp32) ----
#pragma unroll
      for (int r = 0; r < 16; ++r) {
        int rr = mb + crow + (r & 3) + ((r >> 2) << 3);
        G[rr * 64 + nb + ccol] = ca * Xval[r] + cb * Wval[r] + cc * (acUH[r] + acUL[r] * INV_S);
      }
    }
  }
}

// ---------------------------------------------------------------------------
// B4: memory scan + read
// ---------------------------------------------------------------------------
__global__ __launch_bounds__(256) void mem_scan_kernel(const float* __restrict__ chunkS,
                                                       const float* __restrict__ qp,
                                                       const float* __restrict__ galpha,
                                                       float* __restrict__ Mst,
                                                       float* __restrict__ ybuf, int ci) {
  __shared__ float ql[CSz * Dsz];
  __shared__ float al[CSz];
  const int blk = blockIdx.x;
  const int bh = blk >> 4, eb = blk & 15;
  const int b = bh >> 4, h = bh & 15;
  const int tid = threadIdx.x;
  const int w = tid >> 6, lane = tid & 63;
  const int v = eb * 4 + w, k = lane;
  for (int i = tid; i < CSz * Dsz; i += 256) {
    int t = i >> 6, kk = i & 63;
    ql[i] = qp[(((size_t)b * Tsz + ci * CSz + t) * Hsz + h) * Dsz + kk];
  }
  if (tid < CSz) al[tid] = galpha[((size_t)b * Tsz + ci * CSz + tid) * Hsz + h];
  __syncthreads();
  float m = Mst[(size_t)bh * 4096 + v * 64 + k];
  const float* Xo = chunkS + (size_t)bh * CSz * 4096;
  for (int t = 0; t < CSz; ++t) {
    m = al[t] * m + Xo[(size_t)t * 4096 + v * 64 + k];
    float p = m * ql[t * 64 + k];
#pragma unroll
    for (int off = 32; off; off >>= 1) p += __shfl_xor(p, off, 64);
    if (lane == 0) ybuf[(((size_t)b * Tsz + ci * CSz + t) * Hsz + h) * Dsz + v] = p;
  }
  Mst[(size_t)bh * 4096 + v * 64 + k] = m;
}

// ---------------------------------------------------------------------------
extern "C" void kernel_launch(void* const* d_in, const int* in_sizes, int n_in,
                              void* d_out, int out_size, void* d_ws, size_t ws_size,
                              hipStream_t stream) {
  (void)in_sizes; (void)n_in; (void)out_size; (void)ws_size;
  const float* x   = (const float*)d_in[0];
  const float* Wq  = (const float*)d_in[1];
  const float* Wk  = (const float*)d_in[2];
  const float* Wv  = (const float*)d_in[3];
  const float* Wo  = (const float*)d_in[4];
  const float* cqw = (const float*)d_in[5];
  const float* cqb = (const float*)d_in[6];
  const float* ckw = (const float*)d_in[7];
  const float* ckb = (const float*)d_in[8];
  const float* cvw = (const float*)d_in[9];
  const float* cvb = (const float*)d_in[10];
  const float* Wa  = (const float*)d_in[11];
  const float* We  = (const float*)d_in[12];
  const float* Wt  = (const float*)d_in[13];
  const float* Wg  = (const float*)d_in[14];
  float* out = (float*)d_out;

  float* p = (float*)d_ws;
  const size_t NBTC = (size_t)Bsz * Tsz * Csz;
  const size_t NBTH = (size_t)Bsz * Tsz * Hsz;
  const size_t NMAT = (size_t)Bsz * Hsz * Dsz * Dsz;
  float* qlin = p; p += NBTC;
  float* klin = p; p += NBTC;
  float* vlin = p; p += NBTC;
  float* qp   = p; p += NBTC;
  float* kp   = p; p += NBTC;
  float* vp   = p; p += NBTC;
  float* ga   = p; p += NBTH;
  float* ge   = p; p += NBTH;
  float* gt   = p; p += NBTH;
  float* gg   = p; p += NBTH;
  float* Mst  = p; p += NMAT;
  float* Sst  = p; p += NMAT;
  float* chS  = p; p += (size_t)Bsz * Hsz * CSz * Dsz * Dsz;
  float* ybuf = p; p += NBTC;
  float* ynrm = p; p += NBTC;

  hipMemsetAsync(Mst, 0, NMAT * sizeof(float), stream);
  hipMemsetAsync(Sst, 0, NMAT * sizeof(float), stream);

  dim3 gg16(16, 16);
  gemm_nt<<<gg16, 256, 0, stream>>>(x, Wq, qlin, Bsz * Tsz, Csz, Csz);
  gemm_nt<<<gg16, 256, 0, stream>>>(x, Wk, klin, Bsz * Tsz, Csz, Csz);
  gemm_nt<<<gg16, 256, 0, stream>>>(x, Wv, vlin, Bsz * Tsz, Csz, Csz);
  gates_kernel<<<Bsz * Tsz, 64, 0, stream>>>(x, Wa, We, Wt, Wg, ga, ge, gt, gg);
  conv_kernel<<<Bsz * Tsz, 256, 0, stream>>>(qlin, cqw, cqb, qp, 1);
  conv_kernel<<<Bsz * Tsz, 256, 0, stream>>>(klin, ckw, ckb, kp, 1);
  conv_kernel<<<Bsz * Tsz, 256, 0, stream>>>(vlin, cvw, cvb, vp, 0);

  for (int ci = 0; ci < NCHUNK; ++ci) {
    mom_scan_kernel<<<Bsz * Hsz * 16, 256, 0, stream>>>(Mst, kp, vp, ge, gt, gg, Sst, chS, ci);
    pe_mfma_kernel<<<Bsz * Hsz * CSz, 256, 0, stream>>>(chS);
    mem_scan_kernel<<<Bsz * Hsz * 16, 256, 0, stream>>>(chS, qp, ga, Mst, ybuf, ci);
  }

  rms_kernel<<<Bsz * Tsz, 256, 0, stream>>>(ybuf, ynrm);
  gemm_nt<<<gg16, 256, 0, stream>>>(ynrm, Wo, out, Bsz * Tsz, Csz, Csz);
}

// Round 2
// 1197.579 us; speedup vs baseline: 1.0631x; 1.0337x over previous
//
#include <hip/hip_runtime.h>

// Problem constants
constexpr int Bsz = 2, Tsz = 512, Csz = 1024, Hsz = 16, Dsz = 64, CSz = 64;
constexpr int NCHUNK = 8, OW = 8;

typedef __attribute__((ext_vector_type(8))) _Float16 half8;
typedef __attribute__((ext_vector_type(4))) _Float16 half4;
typedef __attribute__((ext_vector_type(16))) float f32x16;

// ---------------------------------------------------------------------------
// Generic tiled GEMM:  O[m][n] = sum_k A[m][k] * W[n][k]   (i.e. A @ W.T)
// ---------------------------------------------------------------------------
__global__ __launch_bounds__(256) void gemm_nt(const float* __restrict__ A,
                                               const float* __restrict__ W,
                                               float* __restrict__ O,
                                               int M, int N, int K) {
  __shared__ float As[16][68];
  __shared__ float Ws[16][68];
  const int tid = threadIdx.x;
  const int m0 = blockIdx.x * 64, n0 = blockIdx.y * 64;
  const int tm = tid & 15, tn = tid >> 4;
  const int lr = tid >> 2, lk = (tid & 3) << 2;
  float acc[4][4] = {};
  for (int k0 = 0; k0 < K; k0 += 16) {
    float4 av = *(const float4*)(A + (size_t)(m0 + lr) * K + k0 + lk);
    float4 wv = *(const float4*)(W + (size_t)(n0 + lr) * K + k0 + lk);
    __syncthreads();
    As[lk + 0][lr] = av.x; As[lk + 1][lr] = av.y; As[lk + 2][lr] = av.z; As[lk + 3][lr] = av.w;
    Ws[lk + 0][lr] = wv.x; Ws[lk + 1][lr] = wv.y; Ws[lk + 2][lr] = wv.z; Ws[lk + 3][lr] = wv.w;
    __syncthreads();
#pragma unroll
    for (int k = 0; k < 16; ++k) {
      float4 a4 = *(const float4*)&As[k][tm << 2];
      float4 w4 = *(const float4*)&Ws[k][tn << 2];
      float a_[4] = {a4.x, a4.y, a4.z, a4.w};
      float w_[4] = {w4.x, w4.y, w4.z, w4.w};
#pragma unroll
      for (int i = 0; i < 4; ++i)
#pragma unroll
        for (int j = 0; j < 4; ++j) acc[i][j] += a_[i] * w_[j];
    }
  }
#pragma unroll
  for (int i = 0; i < 4; ++i) {
    float4 o = {acc[i][0], acc[i][1], acc[i][2], acc[i][3]};
    *(float4*)(O + (size_t)(m0 + (tm << 2) + i) * N + n0 + (tn << 2)) = o;
  }
}

// ---------------------------------------------------------------------------
// Gates
// ---------------------------------------------------------------------------
__global__ __launch_bounds__(64) void gates_kernel(const float* __restrict__ x,
                                                   const float* __restrict__ Wa,
                                                   const float* __restrict__ We,
                                                   const float* __restrict__ Wt,
                                                   const float* __restrict__ Wg,
                                                   float* __restrict__ ga, float* __restrict__ ge,
                                                   float* __restrict__ gt, float* __restrict__ gg) {
  __shared__ float xs[Csz];
  const int bt = blockIdx.x;
  const int tid = threadIdx.x;
  const float* xr = x + (size_t)bt * Csz;
  for (int i = tid * 4; i < Csz; i += 64 * 4) *(float4*)&xs[i] = *(const float4*)&xr[i];
  __syncthreads();
  const int gsel = tid >> 4, h = tid & 15;
  const float* Wrow = (gsel == 0 ? Wa : gsel == 1 ? We : gsel == 2 ? Wt : Wg) + (size_t)h * Csz;
  float acc = 0.f;
  for (int i = 0; i < Csz; i += 4) {
    float4 w4 = *(const float4*)&Wrow[i];
    acc += xs[i] * w4.x + xs[i + 1] * w4.y + xs[i + 2] * w4.z + xs[i + 3] * w4.w;
  }
  float s = 1.f / (1.f + expf(-acc));
  float* outp = (gsel == 0 ? ga : gsel == 1 ? ge : gsel == 2 ? gt : gg);
  outp[(size_t)bt * Hsz + h] = s;
}

// ---------------------------------------------------------------------------
// Causal depthwise conv (K=4) + optional rms_norm/poly
// ---------------------------------------------------------------------------
__global__ __launch_bounds__(256) void conv_kernel(const float* __restrict__ lin,
                                                   const float* __restrict__ w,
                                                   const float* __restrict__ bias,
                                                   float* __restrict__ out, int do_norm) {
  const int bt = blockIdx.x;
  const int b = bt >> 9, t = bt & 511;
  const int tid = threadIdx.x;
  const int c0 = tid << 2;
  float4 bv = *(const float4*)&bias[c0];
  float v0 = bv.x, v1 = bv.y, v2 = bv.z, v3 = bv.w;
  float4 w0 = *(const float4*)&w[(c0 + 0) * 4];
  float4 w1 = *(const float4*)&w[(c0 + 1) * 4];
  float4 w2 = *(const float4*)&w[(c0 + 2) * 4];
  float4 w3 = *(const float4*)&w[(c0 + 3) * 4];
  const float* base = lin + (size_t)b * Tsz * Csz + c0;
#pragma unroll
  for (int j = 0; j < 4; ++j) {
    int tt = t - 3 + j;
    if (tt < 0) continue;
    float4 xv = *(const float4*)(base + (size_t)tt * Csz);
    v0 += xv.x * (&w0.x)[j];
    v1 += xv.y * (&w1.x)[j];
    v2 += xv.z * (&w2.x)[j];
    v3 += xv.w * (&w3.x)[j];
  }
  if (do_norm) {
    float ss = v0 * v0 + v1 * v1 + v2 * v2 + v3 * v3;
    ss += __shfl_xor(ss, 1, 16);
    ss += __shfl_xor(ss, 2, 16);
    ss += __shfl_xor(ss, 4, 16);
    ss += __shfl_xor(ss, 8, 16);
    float scl = rsqrtf(ss * (1.f / 64.f) + 1e-6f);
    v0 *= scl; v1 *= scl; v2 *= scl; v3 *= scl;
    v0 += 0.5f * v0 * v0; v1 += 0.5f * v1 * v1; v2 += 0.5f * v2 * v2; v3 += 0.5f * v3 * v3;
  }
  float4 o = {v0, v1, v2, v3};
  *(float4*)(out + (size_t)bt * Csz + c0) = o;
}

// ---------------------------------------------------------------------------
// rms_norm for y
// ---------------------------------------------------------------------------
__global__ __launch_bounds__(256) void rms_kernel(const float* __restrict__ in,
                                                  float* __restrict__ out) {
  const int bt = blockIdx.x;
  const int tid = threadIdx.x;
  const int c0 = tid << 2;
  float4 xv = *(const float4*)(in + (size_t)bt * Csz + c0);
  float ss = xv.x * xv.x + xv.y * xv.y + xv.z * xv.z + xv.w * xv.w;
  ss += __shfl_xor(ss, 1, 16);
  ss += __shfl_xor(ss, 2, 16);
  ss += __shfl_xor(ss, 4, 16);
  ss += __shfl_xor(ss, 8, 16);
  float scl = rsqrtf(ss * (1.f / 64.f) + 1e-6f);
  float4 o = {xv.x * scl, xv.y * scl, xv.z * scl, xv.w * scl};
  *(float4*)(out + (size_t)bt * Csz + c0) = o;
}

// ---------------------------------------------------------------------------
// B1+B2 fused: err = M k - v  (for this block's 4 v-rows), then
// omega window + momentum scan. Thread per (v,k) element of S.
// ---------------------------------------------------------------------------
__global__ __launch_bounds__(256) void mom_scan_kernel(const float* __restrict__ Mst,
                                                       const float* __restrict__ kp,
                                                       const float* __restrict__ vp,
                                                       const float* __restrict__ geta,
                                                       const float* __restrict__ gtheta,
                                                       const float* __restrict__ ggamma,
                                                       float* __restrict__ Sst,
                                                       float* __restrict__ chunkS, int ci) {
  __shared__ float Ml[4 * Dsz];     // 4 M-rows of this block
  __shared__ float errl[256];       // [t][vloc]
  __shared__ float kkl[CSz * Dsz];  // [t][k]
  __shared__ float gl[CSz], el[CSz], tl[CSz];
  const int blk = blockIdx.x;
  const int bh = blk >> 4, eb = blk & 15;
  const int b = bh >> 4, h = bh & 15;
  const int tid = threadIdx.x;
  Ml[tid & 255] = Mst[(size_t)bh * 4096 + eb * 4 * 64 + tid];
#pragma unroll
  for (int i = 0; i < 16; ++i) {
    int idx = i * 256 + tid;
    int t = idx >> 6, k = idx & 63;
    kkl[idx] = kp[(((size_t)b * Tsz + ci * CSz + t) * Hsz + h) * Dsz + k];
  }
  if (tid < CSz) {
    size_t gi = ((size_t)b * Tsz + ci * CSz + tid) * Hsz + h;
    gl[tid] = ggamma[gi];
    el[tid] = geta[gi];
    tl[tid] = gtheta[gi];
  }
  __syncthreads();
  {
    const int tt = tid >> 2, vl = tid & 3;
    float acc = 0.f;
#pragma unroll 8
    for (int k = 0; k < Dsz; ++k) acc += Ml[vl * 64 + k] * kkl[tt * 64 + k];
    float vv = vp[(((size_t)b * Tsz + ci * CSz + tt) * Hsz + h) * Dsz + eb * 4 + vl];
    errl[tt * 4 + vl] = acc - vv;
  }
  __syncthreads();
  const int e = eb * 256 + tid;
  const int vloc = tid >> 6;
  const int k = tid & 63;
  float S = Sst[(size_t)bh * 4096 + e];
  float ring[OW];
  float wsum = 0.f;
  float* outp = chunkS + (size_t)bh * CSz * 4096 + e;
#pragma unroll
  for (int t = 0; t < CSz; ++t) {
    float u = 2.f * errl[t * 4 + vloc] * kkl[t * 64 + k];
    float val = gl[t] * u;
    wsum += val;
    if (t >= OW) wsum -= ring[t & (OW - 1)];
    ring[t & (OW - 1)] = val;
    S = tl[t] * S - el[t] * wsum;
    outp[(size_t)t * 4096] = S;
  }
  Sst[(size_t)bh * 4096 + e] = S;
}

// ---------------------------------------------------------------------------
// B3: Polar Express via scaled split-f16 MFMA, re-associated dataflow:
//   A = X X^T ; W = A X ; U = A W ; X' = a X + b W + c U
// 4 waves/block, one 32x32 tile each. 3 LDS plane-pairs (X rows / X^T / A);
// W^T ping-pongs into the dead X plane; X' rows into the dead A plane.
// Fully unrolled 5 iterations -> compile-time plane byte offsets; all LDS
// addresses precomputed in VGPRs (loop-invariant incl. XOR bank swizzle).
// fp32 v ~= hi + (lo/2048): products hh -> accH, h*lo + lo*h -> accL.
// ---------------------------------------------------------------------------
__device__ __forceinline__ void split_f16(float v, _Float16& hi, _Float16& lo) {
  _Float16 h = (_Float16)v;                 // RN
  float r = v - (float)h;                   // exact residual
  hi = h;
  lo = (_Float16)(r * 2048.0f);             // RN, scaled into normal range
}

#define MFMA2(accH, accL, ah, al, bh, bl)                                     \
  accH = __builtin_amdgcn_mfma_f32_32x32x16_f16(ah, bh, accH, 0, 0, 0);       \
  accL = __builtin_amdgcn_mfma_f32_32x32x16_f16(ah, bl, accL, 0, 0, 0);       \
  accL = __builtin_amdgcn_mfma_f32_32x32x16_f16(al, bh, accL, 0, 0, 0);

__global__ __launch_bounds__(256, 3) void pe_mfma_kernel(float* __restrict__ chunkS) {
  __shared__ __attribute__((aligned(16))) _Float16 PL[6 * 4096];
  __shared__ float red[4];
  const int tid = threadIdx.x;
  const int lane = tid & 63;
  const int wv = tid >> 6;
  float* G = chunkS + (size_t)blockIdx.x * 4096;
  constexpr float INV_S = 1.0f / 2048.0f;
  constexpr int PLO = 8192;   // hi->lo plane byte distance
  constexpr int PT = 16384;   // X^T plane pair (fixed role)
  char* const LB = (char*)PL;

  const int mb = (wv >> 1) << 5;        // tile row base
  const int nb = (wv & 1) << 5;         // tile col base
  const int crow = ((lane >> 5) << 2);  // C-frag: row = mb+crow+(r&3)+8*(r>>2)
  const int ccol = lane & 31;           // C-frag: col = nb+ccol

  // ---- precompute all LDS byte addresses (loop-invariant) ----
  int ra_m[4], ra_n[4];                 // fragment reads, rows mb / rows nb
#pragma unroll
  for (int ks = 0; ks < 4; ++ks) {
    int rm = mb + (lane & 31), rn = nb + (lane & 31);
    int cB = (ks << 5) + ((lane >> 5) << 4);
    ra_m[ks] = (rm << 7) + (cB ^ ((rm & 7) << 4));
    ra_n[ks] = (rn << 7) + (cB ^ ((rn & 7) << 4));
  }
  int sa[4];                            // transposed sym-store, 4 b64 per plane
  {
    const int base = (nb + ccol) << 7;
    const int sw = ((nb + ccol) & 7) << 4;
    const int c2 = crow << 1;
#pragma unroll
    for (int g = 0; g < 4; ++g) sa[g] = base + ((((mb + 8 * g) << 1) ^ sw) + c2);
  }
  int rowa[4];                          // row-layout scatter store
#pragma unroll
  for (int j = 0; j < 4; ++j) {
    int rr = mb + crow + j;
    rowa[j] = (rr << 7) + (((nb + ccol) << 1) ^ ((rr & 7) << 4));
  }

#define LDF(PB, RA, ks) (*(const half8*)(LB + (PB) + (RA)[ks]))

  // transposed store: plane[col][row] = D[row][col] (for symmetric/transpose targets)
  auto STS = [&](int PB, const _Float16* hs, const _Float16* ls) {
#pragma unroll
    for (int g = 0; g < 4; ++g) {
      half4 hv, lv;
#pragma unroll
      for (int j = 0; j < 4; ++j) { hv[j] = hs[g * 4 + j]; lv[j] = ls[g * 4 + j]; }
      *(half4*)(LB + PB + sa[g]) = hv;
      *(half4*)(LB + PB + PLO + sa[g]) = lv;
    }
  };
  // row store: plane[row][col] = D[row][col]
  auto STR = [&](int PB, const _Float16* hs, const _Float16* ls) {
#pragma unroll
    for (int r = 0; r < 16; ++r) {
      int off = rowa[r & 3] + ((r >> 2) << 10);
      *(_Float16*)(LB + PB + off) = hs[r];
      *(_Float16*)(LB + PB + PLO + off) = ls[r];
    }
  };

  // ---- load in C-frag pattern + Frobenius normalize ----
  float Xval[16];
  float ss = 0.f;
#pragma unroll
  for (int r = 0; r < 16; ++r) {
    int rr = mb + crow + (r & 3) + ((r >> 2) << 3);
    float xv = G[rr * 64 + nb + ccol];
    Xval[r] = xv;
    ss += xv * xv;
  }
#pragma unroll
  for (int off = 32; off; off >>= 1) ss += __shfl_xor(ss, off, 64);
  if (lane == 0) red[wv] = ss;
  __syncthreads();
  float tot = red[0] + red[1] + red[2] + red[3];
  float scale = 1.f / ((sqrtf(tot) + 1e-7f) * 1.01f);

  {
    _Float16 hs[16], ls[16];
#pragma unroll
    for (int r = 0; r < 16; ++r) {
      Xval[r] *= scale;
      split_f16(Xval[r], hs[r], ls[r]);
    }
    STR(0, hs, ls);    // X rows -> plane 0
    STS(PT, hs, ls);   // X^T   -> plane T
  }

  // one PE iteration; PXB/PAB are compile-time-folded plane byte offsets
  auto iter = [&](float ca, float cb, float cc, int PXB, int PAB, bool last) {
    __syncthreads();  // B_a: X rows + X^T visible; prior stage-3 reads drained
    // ---- stage 1: A = X X^T (both operands row-fragments of X) ----
    f32x16 accH, accL;
#pragma unroll
    for (int r = 0; r < 16; ++r) { accH[r] = 0.f; accL[r] = 0.f; }
    __builtin_amdgcn_s_setprio(1);
#pragma unroll
    for (int ks = 0; ks < 4; ++ks) {
      half8 ah = LDF(PXB, ra_m, ks), al = LDF(PXB + PLO, ra_m, ks);
      half8 bh, bl;
      if (mb != nb) { bh = LDF(PXB, ra_n, ks); bl = LDF(PXB + PLO, ra_n, ks); }
      else { bh = ah; bl = al; }
      MFMA2(accH, accL, ah, al, bh, bl);
    }
    __builtin_amdgcn_s_setprio(0);
    {
      _Float16 hs[16], ls[16];
#pragma unroll
      for (int r = 0; r < 16; ++r) split_f16(accH[r] + accL[r] * INV_S, hs[r], ls[r]);
      STS(PAB, hs, ls);  // A (symmetric -> transposed store == A)
    }
    __syncthreads();  // B_b: A ready; stage-1 X reads drained -> PX reusable
    // ---- stage 2: W = A X (A-op rows of A kept in regs; B-op rows of X^T) ----
    half8 fah[4], fal[4];
    f32x16 acWH, acWL;
#pragma unroll
    for (int r = 0; r < 16; ++r) { acWH[r] = 0.f; acWL[r] = 0.f; }
    __builtin_amdgcn_s_setprio(1);
#pragma unroll
    for (int ks = 0; ks < 4; ++ks) {
      fah[ks] = LDF(PAB, ra_m, ks);
      fal[ks] = LDF(PAB + PLO, ra_m, ks);
      half8 bh = LDF(PT, ra_n, ks), bl = LDF(PT + PLO, ra_n, ks);
      MFMA2(acWH, acWL, fah[ks], fal[ks], bh, bl);
    }
    __builtin_amdgcn_s_setprio(0);
    float Wval[16];
    {
      _Float16 hs[16], ls[16];
#pragma unroll
      for (int r = 0; r < 16; ++r) {
        Wval[r] = acWH[r] + acWL[r] * INV_S;
        split_f16(Wval[r], hs[r], ls[r]);
      }
      STS(PXB, hs, ls);  // W^T into dead X plane
    }
    __syncthreads();  // B_c: W^T ready; stage-2 PT/PA reads drained
    // ---- stage 3: U = A W (A-op from regs; B-op rows of W^T) ----
    f32x16 acUH, acUL;
#pragma unroll
    for (int r = 0; r < 16; ++r) { acUH[r] = 0.f; acUL[r] = 0.f; }
    __builtin_amdgcn_s_setprio(1);
#pragma unroll
    for (int ks = 0; ks < 4; ++ks) {
      half8 bh = LDF(PXB, ra_n, ks), bl = LDF(PXB + PLO, ra_n, ks);
      MFMA2(acUH, acUL, fah[ks], fal[ks], bh, bl);
    }
    __builtin_amdgcn_s_setprio(0);
    if (!last) {
      _Float16 hs[16], ls[16];
#pragma unroll
      for (int r = 0; r < 16; ++r) {
        float xn = ca * Xval[r] + cb * Wval[r] + cc * (acUH[r] + acUL[r] * INV_S);
        Xval[r] = xn;
        split_f16(xn, hs[r], ls[r]);
      }
      STR(PAB, hs, ls);  // X' rows -> dead A plane (next iter's PX)
      STS(PT, hs, ls);   // X'^T   -> PT
    } else {
#pragma unroll
      for (int r = 0; r < 16; ++r) {
        int rr = mb + crow + (r & 3) + ((r >> 2) << 3);
        G[rr * 64 + nb + ccol] = ca * Xval[r] + cb * Wval[r] + cc * (acUH[r] + acUL[r] * INV_S);
      }
    }
  };

  iter(8.28721201814563f, -23.595886519098837f, 17.300387312530933f, 0, 32768, false);
  iter(4.107059111542203f, -2.9478499167379106f, 0.5448431082926601f, 32768, 0, false);
  iter(3.9486908534822946f, -2.908902115962949f, 0.5518191394370137f, 0, 32768, false);
  iter(3.3184196573706015f, -2.488488024314874f, 0.51004894012372f, 32768, 0, false);
  iter(2.300652019954817f, -1.6689039845747493f, 0.4188073119525673f, 0, 32768, true);
}

// ---------------------------------------------------------------------------
// B4: memory scan + read
// ---------------------------------------------------------------------------
__global__ __launch_bounds__(256) void mem_scan_kernel(const float* __restrict__ chunkS,
                                                       const float* __restrict__ qp,
                                                       const float* __restrict__ galpha,
                                                       float* __restrict__ Mst,
                                                       float* __restrict__ ybuf, int ci) {
  __shared__ float ql[CSz * Dsz];
  __shared__ float al[CSz];
  const int blk = blockIdx.x;
  const int bh = blk >> 4, eb = blk & 15;
  const int b = bh >> 4, h = bh & 15;
  const int tid = threadIdx.x;
  const int w = tid >> 6, lane = tid & 63;
  const int v = eb * 4 + w, k = lane;
  for (int i = tid; i < CSz * Dsz; i += 256) {
    int t = i >> 6, kk = i & 63;
    ql[i] = qp[(((size_t)b * Tsz + ci * CSz + t) * Hsz + h) * Dsz + kk];
  }
  if (tid < CSz) al[tid] = galpha[((size_t)b * Tsz + ci * CSz + tid) * Hsz + h];
  __syncthreads();
  float m = Mst[(size_t)bh * 4096 + v * 64 + k];
  const float* Xo = chunkS + (size_t)bh * CSz * 4096;
  for (int t = 0; t < CSz; ++t) {
    m = al[t] * m + Xo[(size_t)t * 4096 + v * 64 + k];
    float p = m * ql[t * 64 + k];
#pragma unroll
    for (int off = 32; off; off >>= 1) p += __shfl_xor(p, off, 64);
    if (lane == 0) ybuf[(((size_t)b * Tsz + ci * CSz + t) * Hsz + h) * Dsz + v] = p;
  }
  Mst[(size_t)bh * 4096 + v * 64 + k] = m;
}

// ---------------------------------------------------------------------------
extern "C" void kernel_launch(void* const* d_in, const int* in_sizes, int n_in,
                              void* d_out, int out_size, void* d_ws, size_t ws_size,
                              hipStream_t stream) {
  (void)in_sizes; (void)n_in; (void)out_size; (void)ws_size;
  const float* x   = (const float*)d_in[0];
  const float* Wq  = (const float*)d_in[1];
  const float* Wk  = (const float*)d_in[2];
  const float* Wv  = (const float*)d_in[3];
  const float* Wo  = (const float*)d_in[4];
  const float* cqw = (const float*)d_in[5];
  const float* cqb = (const float*)d_in[6];
  const float* ckw = (const float*)d_in[7];
  const float* ckb = (const float*)d_in[8];
  const float* cvw = (const float*)d_in[9];
  const float* cvb = (const float*)d_in[10];
  const float* Wa  = (const float*)d_in[11];
  const float* We  = (const float*)d_in[12];
  const float* Wt  = (const float*)d_in[13];
  const float* Wg  = (const float*)d_in[14];
  float* out = (float*)d_out;

  float* p = (float*)d_ws;
  const size_t NBTC = (size_t)Bsz * Tsz * Csz;
  const size_t NBTH = (size_t)Bsz * Tsz * Hsz;
  const size_t NMAT = (size_t)Bsz * Hsz * Dsz * Dsz;
  float* qlin = p; p += NBTC;
  float* klin = p; p += NBTC;
  float* vlin = p; p += NBTC;
  float* qp   = p; p += NBTC;
  float* kp   = p; p += NBTC;
  float* vp   = p; p += NBTC;
  float* ga   = p; p += NBTH;
  float* ge   = p; p += NBTH;
  float* gt   = p; p += NBTH;
  float* gg   = p; p += NBTH;
  float* Mst  = p; p += NMAT;
  float* Sst  = p; p += NMAT;
  float* chS  = p; p += (size_t)Bsz * Hsz * CSz * Dsz * Dsz;
  float* ybuf = p; p += NBTC;
  float* ynrm = p; p += NBTC;

  hipMemsetAsync(Mst, 0, NMAT * sizeof(float), stream);
  hipMemsetAsync(Sst, 0, NMAT * sizeof(float), stream);

  dim3 gg16(16, 16);
  gemm_nt<<<gg16, 256, 0, stream>>>(x, Wq, qlin, Bsz * Tsz, Csz, Csz);
  gemm_nt<<<gg16, 256, 0, stream>>>(x, Wk, klin, Bsz * Tsz, Csz, Csz);
  gemm_nt<<<gg16, 256, 0, stream>>>(x, Wv, vlin, Bsz * Tsz, Csz, Csz);
  gates_kernel<<<Bsz * Tsz, 64, 0, stream>>>(x, Wa, We, Wt, Wg, ga, ge, gt, gg);
  conv_kernel<<<Bsz * Tsz, 256, 0, stream>>>(qlin, cqw, cqb, qp, 1);
  conv_kernel<<<Bsz * Tsz, 256, 0, stream>>>(klin, ckw, ckb, kp, 1);
  conv_kernel<<<Bsz * Tsz, 256, 0, stream>>>(vlin, cvw, cvb, vp, 0);

  for (int ci = 0; ci < NCHUNK; ++ci) {
    mom_scan_kernel<<<Bsz * Hsz * 16, 256, 0, stream>>>(Mst, kp, vp, ge, gt, gg, Sst, chS, ci);
    pe_mfma_kernel<<<Bsz * Hsz * CSz, 256, 0, stream>>>(chS);
    mem_scan_kernel<<<Bsz * Hsz * 16, 256, 0, stream>>>(chS, qp, ga, Mst, ybuf, ci);
  }

  rms_kernel<<<Bsz * Tsz, 256, 0, stream>>>(ybuf, ynrm);
  gemm_nt<<<gg16, 256, 0, stream>>>(ynrm, Wo, out, Bsz * Tsz, Csz, Csz);
}

// Round 3
// 1173.152 us; speedup vs baseline: 1.0852x; 1.0208x over previous
//
#include <hip/hip_runtime.h>

// Problem constants
constexpr int Bsz = 2, Tsz = 512, Csz = 1024, Hsz = 16, Dsz = 64, CSz = 64;
constexpr int NCHUNK = 8, OW = 8;

typedef __attribute__((ext_vector_type(8))) _Float16 half8;
typedef __attribute__((ext_vector_type(4))) _Float16 half4;
typedef __attribute__((ext_vector_type(16))) float f32x16;

// ---------------------------------------------------------------------------
// Generic tiled GEMM:  O[m][n] = sum_k A[m][k] * W[n][k]   (i.e. A @ W.T)
// (used for the final out-projection only)
// ---------------------------------------------------------------------------
__global__ __launch_bounds__(256) void gemm_nt(const float* __restrict__ A,
                                               const float* __restrict__ W,
                                               float* __restrict__ O,
                                               int M, int N, int K) {
  __shared__ float As[16][68];
  __shared__ float Ws[16][68];
  const int tid = threadIdx.x;
  const int m0 = blockIdx.x * 64, n0 = blockIdx.y * 64;
  const int tm = tid & 15, tn = tid >> 4;
  const int lr = tid >> 2, lk = (tid & 3) << 2;
  float acc[4][4] = {};
  for (int k0 = 0; k0 < K; k0 += 16) {
    float4 av = *(const float4*)(A + (size_t)(m0 + lr) * K + k0 + lk);
    float4 wv = *(const float4*)(W + (size_t)(n0 + lr) * K + k0 + lk);
    __syncthreads();
    As[lk + 0][lr] = av.x; As[lk + 1][lr] = av.y; As[lk + 2][lr] = av.z; As[lk + 3][lr] = av.w;
    Ws[lk + 0][lr] = wv.x; Ws[lk + 1][lr] = wv.y; Ws[lk + 2][lr] = wv.z; Ws[lk + 3][lr] = wv.w;
    __syncthreads();
#pragma unroll
    for (int k = 0; k < 16; ++k) {
      float4 a4 = *(const float4*)&As[k][tm << 2];
      float4 w4 = *(const float4*)&Ws[k][tn << 2];
      float a_[4] = {a4.x, a4.y, a4.z, a4.w};
      float w_[4] = {w4.x, w4.y, w4.z, w4.w};
#pragma unroll
      for (int i = 0; i < 4; ++i)
#pragma unroll
        for (int j = 0; j < 4; ++j) acc[i][j] += a_[i] * w_[j];
    }
  }
#pragma unroll
  for (int i = 0; i < 4; ++i) {
    float4 o = {acc[i][0], acc[i][1], acc[i][2], acc[i][3]};
    *(float4*)(O + (size_t)(m0 + (tm << 2) + i) * N + n0 + (tn << 2)) = o;
  }
}

// ---------------------------------------------------------------------------
// Fused QKV + gates GEMM. Grid (16, 49):
//   y in [0,48): mat = y>>4 selects Wq/Wk/Wv -> qlin/klin/vlin, n0=(y&15)*64
//   y == 48   : 64 gate rows (4 mats x 16 heads) + sigmoid -> ga/ge/gt/gg
// ---------------------------------------------------------------------------
__global__ __launch_bounds__(256) void qkvg_gemm(const float* __restrict__ x,
                                                 const float* __restrict__ Wq,
                                                 const float* __restrict__ Wk,
                                                 const float* __restrict__ Wv,
                                                 const float* __restrict__ Wa,
                                                 const float* __restrict__ We,
                                                 const float* __restrict__ Wt,
                                                 const float* __restrict__ Wg,
                                                 float* __restrict__ qlin,
                                                 float* __restrict__ klin,
                                                 float* __restrict__ vlin,
                                                 float* __restrict__ ga, float* __restrict__ ge,
                                                 float* __restrict__ gt, float* __restrict__ gg) {
  __shared__ float As[16][68];
  __shared__ float Ws[16][68];
  const int tid = threadIdx.x;
  const int by = blockIdx.y;
  const int m0 = blockIdx.x * 64;
  const int tm = tid & 15, tn = tid >> 4;
  const int lr = tid >> 2, lk = (tid & 3) << 2;
  const bool is_gate = (by == 48);
  const float* Wrow;
  if (!is_gate) {
    const int mat = by >> 4, n0 = (by & 15) * 64;
    const float* W = (mat == 0 ? Wq : mat == 1 ? Wk : Wv);
    Wrow = W + (size_t)(n0 + lr) * Csz;
  } else {
    const int gsel = lr >> 4;
    const float* W = (gsel == 0 ? Wa : gsel == 1 ? We : gsel == 2 ? Wt : Wg);
    Wrow = W + (size_t)(lr & 15) * Csz;
  }
  const float* Arow = x + (size_t)(m0 + lr) * Csz;
  float acc[4][4] = {};
  for (int k0 = 0; k0 < Csz; k0 += 16) {
    float4 av = *(const float4*)(Arow + k0 + lk);
    float4 wv = *(const float4*)(Wrow + k0 + lk);
    __syncthreads();
    As[lk + 0][lr] = av.x; As[lk + 1][lr] = av.y; As[lk + 2][lr] = av.z; As[lk + 3][lr] = av.w;
    Ws[lk + 0][lr] = wv.x; Ws[lk + 1][lr] = wv.y; Ws[lk + 2][lr] = wv.z; Ws[lk + 3][lr] = wv.w;
    __syncthreads();
#pragma unroll
    for (int k = 0; k < 16; ++k) {
      float4 a4 = *(const float4*)&As[k][tm << 2];
      float4 w4 = *(const float4*)&Ws[k][tn << 2];
      float a_[4] = {a4.x, a4.y, a4.z, a4.w};
      float w_[4] = {w4.x, w4.y, w4.z, w4.w};
#pragma unroll
      for (int i = 0; i < 4; ++i)
#pragma unroll
        for (int j = 0; j < 4; ++j) acc[i][j] += a_[i] * w_[j];
    }
  }
  if (!is_gate) {
    const int mat = by >> 4, n0 = (by & 15) * 64;
    float* O = (mat == 0 ? qlin : mat == 1 ? klin : vlin);
#pragma unroll
    for (int i = 0; i < 4; ++i) {
      float4 o = {acc[i][0], acc[i][1], acc[i][2], acc[i][3]};
      *(float4*)(O + (size_t)(m0 + (tm << 2) + i) * Csz + n0 + (tn << 2)) = o;
    }
  } else {
    // cols c = 4*tn + j ; gsel = c>>4 constant per thread, h = c&15 contiguous
    const int gsel = tn >> 2;
    const int h0 = (tn << 2) & 15;
    float* outp = (gsel == 0 ? ga : gsel == 1 ? ge : gsel == 2 ? gt : gg);
#pragma unroll
    for (int i = 0; i < 4; ++i) {
      const int bt = m0 + (tm << 2) + i;
      float4 o;
#pragma unroll
      for (int j = 0; j < 4; ++j) (&o.x)[j] = 1.f / (1.f + expf(-acc[i][j]));
      *(float4*)(outp + (size_t)bt * Hsz + h0) = o;
    }
  }
}

// ---------------------------------------------------------------------------
// Causal depthwise conv (K=4) + optional rms_norm/poly. Grid (B*T, 3):
// blockIdx.y selects q/k/v stream; norm applied for q,k only.
// ---------------------------------------------------------------------------
__global__ __launch_bounds__(256) void conv3_kernel(const float* __restrict__ qlin,
                                                    const float* __restrict__ klin,
                                                    const float* __restrict__ vlin,
                                                    const float* __restrict__ cqw,
                                                    const float* __restrict__ ckw,
                                                    const float* __restrict__ cvw,
                                                    const float* __restrict__ cqb,
                                                    const float* __restrict__ ckb,
                                                    const float* __restrict__ cvb,
                                                    float* __restrict__ qp,
                                                    float* __restrict__ kp,
                                                    float* __restrict__ vp) {
  const int sel = blockIdx.y;
  const float* lin = (sel == 0 ? qlin : sel == 1 ? klin : vlin);
  const float* w = (sel == 0 ? cqw : sel == 1 ? ckw : cvw);
  const float* bias = (sel == 0 ? cqb : sel == 1 ? ckb : cvb);
  float* out = (sel == 0 ? qp : sel == 1 ? kp : vp);
  const int do_norm = (sel < 2);
  const int bt = blockIdx.x;
  const int b = bt >> 9, t = bt & 511;
  const int tid = threadIdx.x;
  const int c0 = tid << 2;
  float4 bv = *(const float4*)&bias[c0];
  float v0 = bv.x, v1 = bv.y, v2 = bv.z, v3 = bv.w;
  float4 w0 = *(const float4*)&w[(c0 + 0) * 4];
  float4 w1 = *(const float4*)&w[(c0 + 1) * 4];
  float4 w2 = *(const float4*)&w[(c0 + 2) * 4];
  float4 w3 = *(const float4*)&w[(c0 + 3) * 4];
  const float* base = lin + (size_t)b * Tsz * Csz + c0;
#pragma unroll
  for (int j = 0; j < 4; ++j) {
    int tt = t - 3 + j;
    if (tt < 0) continue;
    float4 xv = *(const float4*)(base + (size_t)tt * Csz);
    v0 += xv.x * (&w0.x)[j];
    v1 += xv.y * (&w1.x)[j];
    v2 += xv.z * (&w2.x)[j];
    v3 += xv.w * (&w3.x)[j];
  }
  if (do_norm) {
    float ss = v0 * v0 + v1 * v1 + v2 * v2 + v3 * v3;
    ss += __shfl_xor(ss, 1, 16);
    ss += __shfl_xor(ss, 2, 16);
    ss += __shfl_xor(ss, 4, 16);
    ss += __shfl_xor(ss, 8, 16);
    float scl = rsqrtf(ss * (1.f / 64.f) + 1e-6f);
    v0 *= scl; v1 *= scl; v2 *= scl; v3 *= scl;
    v0 += 0.5f * v0 * v0; v1 += 0.5f * v1 * v1; v2 += 0.5f * v2 * v2; v3 += 0.5f * v3 * v3;
  }
  float4 o = {v0, v1, v2, v3};
  *(float4*)(out + (size_t)bt * Csz + c0) = o;
}

// ---------------------------------------------------------------------------
// rms_norm for y
// ---------------------------------------------------------------------------
__global__ __launch_bounds__(256) void rms_kernel(const float* __restrict__ in,
                                                  float* __restrict__ out) {
  const int bt = blockIdx.x;
  const int tid = threadIdx.x;
  const int c0 = tid << 2;
  float4 xv = *(const float4*)(in + (size_t)bt * Csz + c0);
  float ss = xv.x * xv.x + xv.y * xv.y + xv.z * xv.z + xv.w * xv.w;
  ss += __shfl_xor(ss, 1, 16);
  ss += __shfl_xor(ss, 2, 16);
  ss += __shfl_xor(ss, 4, 16);
  ss += __shfl_xor(ss, 8, 16);
  float scl = rsqrtf(ss * (1.f / 64.f) + 1e-6f);
  float4 o = {xv.x * scl, xv.y * scl, xv.z * scl, xv.w * scl};
  *(float4*)(out + (size_t)bt * Csz + c0) = o;
}

// ---------------------------------------------------------------------------
// Standalone momentum scan (chunk 0 only): err = M k - v, omega window,
// momentum scan. Thread per (v,k) element of S.
// ---------------------------------------------------------------------------
__global__ __launch_bounds__(256) void mom_scan_kernel(const float* __restrict__ Mst,
                                                       const float* __restrict__ kp,
                                                       const float* __restrict__ vp,
                                                       const float* __restrict__ geta,
                                                       const float* __restrict__ gtheta,
                                                       const float* __restrict__ ggamma,
                                                       float* __restrict__ Sst,
                                                       float* __restrict__ chunkS, int ci) {
  __shared__ float Ml[4 * Dsz];
  __shared__ float errl[256];
  __shared__ float kkl[CSz * Dsz];
  __shared__ float gl[CSz], el[CSz], tl[CSz];
  const int blk = blockIdx.x;
  const int bh = blk >> 4, eb = blk & 15;
  const int b = bh >> 4, h = bh & 15;
  const int tid = threadIdx.x;
  Ml[tid & 255] = Mst[(size_t)bh * 4096 + eb * 4 * 64 + tid];
#pragma unroll
  for (int i = 0; i < 16; ++i) {
    int idx = i * 256 + tid;
    int t = idx >> 6, k = idx & 63;
    kkl[idx] = kp[(((size_t)b * Tsz + ci * CSz + t) * Hsz + h) * Dsz + k];
  }
  if (tid < CSz) {
    size_t gi = ((size_t)b * Tsz + ci * CSz + tid) * Hsz + h;
    gl[tid] = ggamma[gi];
    el[tid] = geta[gi];
    tl[tid] = gtheta[gi];
  }
  __syncthreads();
  {
    const int tt = tid >> 2, vl = tid & 3;
    float acc = 0.f;
#pragma unroll
    for (int i = 0; i < 16; ++i) {
      float4 m4 = *(const float4*)&Ml[vl * 64 + i * 4];
      float4 k4 = *(const float4*)&kkl[tt * 64 + i * 4];
      acc += m4.x * k4.x + m4.y * k4.y + m4.z * k4.z + m4.w * k4.w;
    }
    float vv = vp[(((size_t)b * Tsz + ci * CSz + tt) * Hsz + h) * Dsz + eb * 4 + vl];
    errl[tt * 4 + vl] = acc - vv;
  }
  __syncthreads();
  const int e = eb * 256 + tid;
  const int vloc = tid >> 6;
  const int k = tid & 63;
  float S = Sst[(size_t)bh * 4096 + e];
  float ring[OW];
  float wsum = 0.f;
  float* outp = chunkS + (size_t)bh * CSz * 4096 + e;
#pragma unroll
  for (int t = 0; t < CSz; ++t) {
    float u = 2.f * errl[t * 4 + vloc] * kkl[t * 64 + k];
    float val = gl[t] * u;
    wsum += val;
    if (t >= OW) wsum -= ring[t & (OW - 1)];
    ring[t & (OW - 1)] = val;
    S = tl[t] * S - el[t] * wsum;
    outp[(size_t)t * 4096] = S;
  }
  Sst[(size_t)bh * 4096 + e] = S;
}

// ---------------------------------------------------------------------------
// Fused: memory scan + read (chunk ci), then momentum scan (chunk ci+1).
// Block (bh,eb) updates exactly the M rows [eb*4, eb*4+4) that its mom part
// needs for err -> M never round-trips to HBM between the two phases.
// chunkS in/out alias is safe: each thread reads then overwrites only its
// own (v,k) element (program order).
// ---------------------------------------------------------------------------
__global__ __launch_bounds__(256) void fused_scan_kernel(float* __restrict__ chunkS,
                                                         const float* __restrict__ qp,
                                                         const float* __restrict__ kp,
                                                         const float* __restrict__ vp,
                                                         const float* __restrict__ galpha,
                                                         const float* __restrict__ geta,
                                                         const float* __restrict__ gtheta,
                                                         const float* __restrict__ ggamma,
                                                         float* __restrict__ Mst,
                                                         float* __restrict__ Sst,
                                                         float* __restrict__ ybuf,
                                                         int ci, int do_next) {
  __shared__ float buf[CSz * Dsz];  // ql (mem phase) then kkl (mom phase)
  __shared__ float al[CSz];
  __shared__ float Ml[4 * Dsz];
  __shared__ float errl[256];
  __shared__ float gl[CSz], el[CSz], tl[CSz];
  const int blk = blockIdx.x;
  const int bh = blk >> 4, eb = blk & 15;
  const int b = bh >> 4, h = bh & 15;
  const int tid = threadIdx.x;
  const int w = tid >> 6, lane = tid & 63;
  const int v = eb * 4 + w, k = lane;
  // ---- mem phase (chunk ci) ----
  for (int i = tid; i < CSz * Dsz; i += 256) {
    int t = i >> 6, kk = i & 63;
    buf[i] = qp[(((size_t)b * Tsz + ci * CSz + t) * Hsz + h) * Dsz + kk];
  }
  if (tid < CSz) al[tid] = galpha[((size_t)b * Tsz + ci * CSz + tid) * Hsz + h];
  __syncthreads();
  float m = Mst[(size_t)bh * 4096 + v * 64 + k];
  const float* Xo = chunkS + (size_t)bh * CSz * 4096;
  for (int t = 0; t < CSz; ++t) {
    m = al[t] * m + Xo[(size_t)t * 4096 + v * 64 + k];
    float p = m * buf[t * 64 + k];
#pragma unroll
    for (int off = 32; off; off >>= 1) p += __shfl_xor(p, off, 64);
    if (lane == 0) ybuf[(((size_t)b * Tsz + ci * CSz + t) * Hsz + h) * Dsz + v] = p;
  }
  Mst[(size_t)bh * 4096 + v * 64 + k] = m;
  if (!do_next) return;
  Ml[w * 64 + k] = m;
  __syncthreads();  // ql reads done (buf reusable); Ml visible
  // ---- mom phase (chunk ci+1) ----
  const int cj = ci + 1;
#pragma unroll
  for (int i = 0; i < 16; ++i) {
    int idx = i * 256 + tid;
    int t = idx >> 6, kk = idx & 63;
    buf[idx] = kp[(((size_t)b * Tsz + cj * CSz + t) * Hsz + h) * Dsz + kk];
  }
  if (tid < CSz) {
    size_t gi = ((size_t)b * Tsz + cj * CSz + tid) * Hsz + h;
    gl[tid] = ggamma[gi];
    el[tid] = geta[gi];
    tl[tid] = gtheta[gi];
  }
  __syncthreads();
  {
    const int tt = tid >> 2, vl = tid & 3;
    float acc = 0.f;
#pragma unroll
    for (int i = 0; i < 16; ++i) {
      float4 m4 = *(const float4*)&Ml[vl * 64 + i * 4];
      float4 k4 = *(const float4*)&buf[tt * 64 + i * 4];
      acc += m4.x * k4.x + m4.y * k4.y + m4.z * k4.z + m4.w * k4.w;
    }
    float vv = vp[(((size_t)b * Tsz + cj * CSz + tt) * Hsz + h) * Dsz + eb * 4 + vl];
    errl[tt * 4 + vl] = acc - vv;
  }
  __syncthreads();
  const int e = eb * 256 + tid;
  const int vloc = tid >> 6;
  float S = Sst[(size_t)bh * 4096 + e];
  float ring[OW];
  float wsum = 0.f;
  float* outp = chunkS + (size_t)bh * CSz * 4096 + e;
#pragma unroll
  for (int t = 0; t < CSz; ++t) {
    float u = 2.f * errl[t * 4 + vloc] * buf[t * 64 + k];
    float val = gl[t] * u;
    wsum += val;
    if (t >= OW) wsum -= ring[t & (OW - 1)];
    ring[t & (OW - 1)] = val;
    S = tl[t] * S - el[t] * wsum;
    outp[(size_t)t * 4096] = S;
  }
  Sst[(size_t)bh * 4096 + e] = S;
}

// ---------------------------------------------------------------------------
// B3: Polar Express via scaled split-f16 MFMA, re-associated dataflow:
//   A = X X^T ; W = A X ; U = A W ; X' = a X + b W + c U
// 4 waves/block, one 32x32 tile each. 3 LDS plane-pairs (X rows / X^T / A);
// W^T ping-pongs into the dead X plane; X' rows into the dead A plane.
// Stage-1 symmetry: wave 2's tile is wave 1's transpose -> wave 2 skips
// stage-1 compute; wave 1 writes both A regions (STS lands in region (1,0),
// STR in region (0,1)).
// fp32 v ~= hi + (lo/2048): products hh -> accH, h*lo + lo*h -> accL.
// ---------------------------------------------------------------------------
__device__ __forceinline__ void split_f16(float v, _Float16& hi, _Float16& lo) {
  _Float16 h = (_Float16)v;                 // RN
  float r = v - (float)h;                   // exact residual
  hi = h;
  lo = (_Float16)(r * 2048.0f);             // RN, scaled into normal range
}

#define MFMA2(accH, accL, ah, al, bh, bl)                                     \
  accH = __builtin_amdgcn_mfma_f32_32x32x16_f16(ah, bh, accH, 0, 0, 0);       \
  accL = __builtin_amdgcn_mfma_f32_32x32x16_f16(ah, bl, accL, 0, 0, 0);       \
  accL = __builtin_amdgcn_mfma_f32_32x32x16_f16(al, bh, accL, 0, 0, 0);

__global__ __launch_bounds__(256, 3) void pe_mfma_kernel(float* __restrict__ chunkS) {
  __shared__ __attribute__((aligned(16))) _Float16 PL[6 * 4096];
  __shared__ float red[4];
  const int tid = threadIdx.x;
  const int lane = tid & 63;
  const int wv = tid >> 6;
  float* G = chunkS + (size_t)blockIdx.x * 4096;
  constexpr float INV_S = 1.0f / 2048.0f;
  constexpr int PLO = 8192;   // hi->lo plane byte distance
  constexpr int PT = 16384;   // X^T plane pair (fixed role)
  char* const LB = (char*)PL;

  const int mb = (wv >> 1) << 5;        // tile row base
  const int nb = (wv & 1) << 5;         // tile col base
  const int crow = ((lane >> 5) << 2);  // C-frag: row = mb+crow+(r&3)+8*(r>>2)
  const int ccol = lane & 31;           // C-frag: col = nb+ccol

  // ---- precompute all LDS byte addresses (loop-invariant) ----
  int ra_m[4], ra_n[4];                 // fragment reads, rows mb / rows nb
#pragma unroll
  for (int ks = 0; ks < 4; ++ks) {
    int rm = mb + (lane & 31), rn = nb + (lane & 31);
    int cB = (ks << 5) + ((lane >> 5) << 4);
    ra_m[ks] = (rm << 7) + (cB ^ ((rm & 7) << 4));
    ra_n[ks] = (rn << 7) + (cB ^ ((rn & 7) << 4));
  }
  int sa[4];                            // transposed sym-store, 4 b64 per plane
  {
    const int base = (nb + ccol) << 7;
    const int sw = ((nb + ccol) & 7) << 4;
    const int c2 = crow << 1;
#pragma unroll
    for (int g = 0; g < 4; ++g) sa[g] = base + ((((mb + 8 * g) << 1) ^ sw) + c2);
  }
  int rowa[4];                          // row-layout scatter store
#pragma unroll
  for (int j = 0; j < 4; ++j) {
    int rr = mb + crow + j;
    rowa[j] = (rr << 7) + (((nb + ccol) << 1) ^ ((rr & 7) << 4));
  }

#define LDF(PB, RA, ks) (*(const half8*)(LB + (PB) + (RA)[ks]))

  // transposed store: plane[col][row] = D[row][col]
  auto STS = [&](int PB, const _Float16* hs, const _Float16* ls) {
#pragma unroll
    for (int g = 0; g < 4; ++g) {
      half4 hv, lv;
#pragma unroll
      for (int j = 0; j < 4; ++j) { hv[j] = hs[g * 4 + j]; lv[j] = ls[g * 4 + j]; }
      *(half4*)(LB + PB + sa[g]) = hv;
      *(half4*)(LB + PB + PLO + sa[g]) = lv;
    }
  };
  // row store: plane[row][col] = D[row][col]
  auto STR = [&](int PB, const _Float16* hs, const _Float16* ls) {
#pragma unroll
    for (int r = 0; r < 16; ++r) {
      int off = rowa[r & 3] + ((r >> 2) << 10);
      *(_Float16*)(LB + PB + off) = hs[r];
      *(_Float16*)(LB + PB + PLO + off) = ls[r];
    }
  };

  // ---- load in C-frag pattern + Frobenius normalize ----
  float Xval[16];
  float ss = 0.f;
#pragma unroll
  for (int r = 0; r < 16; ++r) {
    int rr = mb + crow + (r & 3) + ((r >> 2) << 3);
    float xv = G[rr * 64 + nb + ccol];
    Xval[r] = xv;
    ss += xv * xv;
  }
#pragma unroll
  for (int off = 32; off; off >>= 1) ss += __shfl_xor(ss, off, 64);
  if (lane == 0) red[wv] = ss;
  __syncthreads();
  float tot = red[0] + red[1] + red[2] + red[3];
  float scale = 1.f / ((sqrtf(tot) + 1e-7f) * 1.01f);

  {
    _Float16 hs[16], ls[16];
#pragma unroll
    for (int r = 0; r < 16; ++r) {
      Xval[r] *= scale;
      split_f16(Xval[r], hs[r], ls[r]);
    }
    STR(0, hs, ls);    // X rows -> plane 0
    STS(PT, hs, ls);   // X^T   -> plane T
  }

  // one PE iteration; PXB/PAB are compile-time-folded plane byte offsets
  auto iter = [&](float ca, float cb, float cc, int PXB, int PAB, bool last) {
    __syncthreads();  // B_a: X rows + X^T visible; prior stage-3 reads drained
    // ---- stage 1: A = X X^T (wave 2 redundant by symmetry -> skips) ----
    if (wv != 2) {
      f32x16 accH, accL;
#pragma unroll
      for (int r = 0; r < 16; ++r) { accH[r] = 0.f; accL[r] = 0.f; }
      __builtin_amdgcn_s_setprio(1);
#pragma unroll
      for (int ks = 0; ks < 4; ++ks) {
        half8 ah = LDF(PXB, ra_m, ks), al = LDF(PXB + PLO, ra_m, ks);
        half8 bh, bl;
        if (mb != nb) { bh = LDF(PXB, ra_n, ks); bl = LDF(PXB + PLO, ra_n, ks); }
        else { bh = ah; bl = al; }
        MFMA2(accH, accL, ah, al, bh, bl);
      }
      __builtin_amdgcn_s_setprio(0);
      _Float16 hs[16], ls[16];
#pragma unroll
      for (int r = 0; r < 16; ++r) split_f16(accH[r] + accL[r] * INV_S, hs[r], ls[r]);
      STS(PAB, hs, ls);                  // writes transposed region
      if (wv == 1) STR(PAB, hs, ls);     // wave 1 also writes its own region
    }
    __syncthreads();  // B_b: A ready; stage-1 X reads drained -> PX reusable
    // ---- stage 2: W = A X (A-op rows of A kept in regs; B-op rows of X^T) ----
    half8 fah[4], fal[4];
    f32x16 acWH, acWL;
#pragma unroll
    for (int r = 0; r < 16; ++r) { acWH[r] = 0.f; acWL[r] = 0.f; }
    __builtin_amdgcn_s_setprio(1);
#pragma unroll
    for (int ks = 0; ks < 4; ++ks) {
      fah[ks] = LDF(PAB, ra_m, ks);
      fal[ks] = LDF(PAB + PLO, ra_m, ks);
      half8 bh = LDF(PT, ra_n, ks), bl = LDF(PT + PLO, ra_n, ks);
      MFMA2(acWH, acWL, fah[ks], fal[ks], bh, bl);
    }
    __builtin_amdgcn_s_setprio(0);
    float Wval[16];
    {
      _Float16 hs[16], ls[16];
#pragma unroll
      for (int r = 0; r < 16; ++r) {
        Wval[r] = acWH[r] + acWL[r] * INV_S;
        split_f16(Wval[r], hs[r], ls[r]);
      }
      STS(PXB, hs, ls);  // W^T into dead X plane
    }
    __syncthreads();  // B_c: W^T ready; stage-2 PT/PA reads drained
    // ---- stage 3: U = A W (A-op from regs; B-op rows of W^T) ----
    f32x16 acUH, acUL;
#pragma unroll
    for (int r = 0; r < 16; ++r) { acUH[r] = 0.f; acUL[r] = 0.f; }
    __builtin_amdgcn_s_setprio(1);
#pragma unroll
    for (int ks = 0; ks < 4; ++ks) {
      half8 bh = LDF(PXB, ra_n, ks), bl = LDF(PXB + PLO, ra_n, ks);
      MFMA2(acUH, acUL, fah[ks], fal[ks], bh, bl);
    }
    __builtin_amdgcn_s_setprio(0);
    if (!last) {
      _Float16 hs[16], ls[16];
#pragma unroll
      for (int r = 0; r < 16; ++r) {
        float xn = ca * Xval[r] + cb * Wval[r] + cc * (acUH[r] + acUL[r] * INV_S);
        Xval[r] = xn;
        split_f16(xn, hs[r], ls[r]);
      }
      STR(PAB, hs, ls);  // X' rows -> dead A plane (next iter's PX)
      STS(PT, hs, ls);   // X'^T   -> PT
    } else {
#pragma unroll
      for (int r = 0; r < 16; ++r) {
        int rr = mb + crow + (r & 3) + ((r >> 2) << 3);
        G[rr * 64 + nb + ccol] = ca * Xval[r] + cb * Wval[r] + cc * (acUH[r] + acUL[r] * INV_S);
      }
    }
  };

  iter(8.28721201814563f, -23.595886519098837f, 17.300387312530933f, 0, 32768, false);
  iter(4.107059111542203f, -2.9478499167379106f, 0.5448431082926601f, 32768, 0, false);
  iter(3.9486908534822946f, -2.908902115962949f, 0.5518191394370137f, 0, 32768, false);
  iter(3.3184196573706015f, -2.488488024314874f, 0.51004894012372f, 32768, 0, false);
  iter(2.300652019954817f, -1.6689039845747493f, 0.4188073119525673f, 0, 32768, true);
}

// ---------------------------------------------------------------------------
extern "C" void kernel_launch(void* const* d_in, const int* in_sizes, int n_in,
                              void* d_out, int out_size, void* d_ws, size_t ws_size,
                              hipStream_t stream) {
  (void)in_sizes; (void)n_in; (void)out_size; (void)ws_size;
  const float* x   = (const float*)d_in[0];
  const float* Wq  = (const float*)d_in[1];
  const float* Wk  = (const float*)d_in[2];
  const float* Wv  = (const float*)d_in[3];
  const float* Wo  = (const float*)d_in[4];
  const float* cqw = (const float*)d_in[5];
  const float* cqb = (const float*)d_in[6];
  const float* ckw = (const float*)d_in[7];
  const float* ckb = (const float*)d_in[8];
  const float* cvw = (const float*)d_in[9];
  const float* cvb = (const float*)d_in[10];
  const float* Wa  = (const float*)d_in[11];
  const float* We  = (const float*)d_in[12];
  const float* Wt  = (const float*)d_in[13];
  const float* Wg  = (const float*)d_in[14];
  float* out = (float*)d_out;

  float* p = (float*)d_ws;
  const size_t NBTC = (size_t)Bsz * Tsz * Csz;
  const size_t NBTH = (size_t)Bsz * Tsz * Hsz;
  const size_t NMAT = (size_t)Bsz * Hsz * Dsz * Dsz;
  float* qlin = p; p += NBTC;
  float* klin = p; p += NBTC;
  float* vlin = p; p += NBTC;
  float* qp   = p; p += NBTC;
  float* kp   = p; p += NBTC;
  float* vp   = p; p += NBTC;
  float* ga   = p; p += NBTH;
  float* ge   = p; p += NBTH;
  float* gt   = p; p += NBTH;
  float* gg   = p; p += NBTH;
  float* Mst  = p; p += NMAT;
  float* Sst  = p; p += NMAT;
  float* chS  = p; p += (size_t)Bsz * Hsz * CSz * Dsz * Dsz;
  float* ybuf = p; p += NBTC;
  float* ynrm = p; p += NBTC;

  hipMemsetAsync(Mst, 0, NMAT * sizeof(float), stream);
  hipMemsetAsync(Sst, 0, NMAT * sizeof(float), stream);

  qkvg_gemm<<<dim3(16, 49), 256, 0, stream>>>(x, Wq, Wk, Wv, Wa, We, Wt, Wg,
                                              qlin, klin, vlin, ga, ge, gt, gg);
  conv3_kernel<<<dim3(Bsz * Tsz, 3), 256, 0, stream>>>(qlin, klin, vlin, cqw, ckw, cvw,
                                                       cqb, ckb, cvb, qp, kp, vp);

  mom_scan_kernel<<<Bsz * Hsz * 16, 256, 0, stream>>>(Mst, kp, vp, ge, gt, gg, Sst, chS, 0);
  for (int ci = 0; ci < NCHUNK; ++ci) {
    pe_mfma_kernel<<<Bsz * Hsz * CSz, 256, 0, stream>>>(chS);
    fused_scan_kernel<<<Bsz * Hsz * 16, 256, 0, stream>>>(chS, qp, kp, vp, ga, ge, gt, gg,
                                                          Mst, Sst, ybuf, ci,
                                                          ci < NCHUNK - 1 ? 1 : 0);
  }

  rms_kernel<<<Bsz * Tsz, 256, 0, stream>>>(ybuf, ynrm);
  gemm_nt<<<dim3(16, 16), 256, 0, stream>>>(ynrm, Wo, out, Bsz * Tsz, Csz, Csz);
}

// Round 4
// 1010.162 us; speedup vs baseline: 1.2603x; 1.1614x over previous
//
#include <hip/hip_runtime.h>

// Problem constants
constexpr int Bsz = 2, Tsz = 512, Csz = 1024, Hsz = 16, Dsz = 64, CSz = 64;
constexpr int NCHUNK = 8, OW = 8;

typedef __attribute__((ext_vector_type(8))) _Float16 half8;
typedef __attribute__((ext_vector_type(4))) _Float16 half4;
typedef __attribute__((ext_vector_type(16))) float f32x16;

constexpr float INV_S = 1.0f / 2048.0f;

// fp32 v ~= hi + lo/2048 (f16 pair). Proven precision-adequate by pe kernel.
__device__ __forceinline__ void split_f16(float v, _Float16& hi, _Float16& lo) {
  _Float16 h = (_Float16)v;
  float r = v - (float)h;
  hi = h;
  lo = (_Float16)(r * 2048.0f);
}

#define MFMA2(accH, accL, ah, al, bh, bl)                                     \
  accH = __builtin_amdgcn_mfma_f32_32x32x16_f16(ah, bh, accH, 0, 0, 0);       \
  accL = __builtin_amdgcn_mfma_f32_32x32x16_f16(ah, bl, accL, 0, 0, 0);       \
  accL = __builtin_amdgcn_mfma_f32_32x32x16_f16(al, bh, accL, 0, 0, 0);

// ---------------------------------------------------------------------------
// One-time fp32 -> (hi,lo) f16 plane conversion.
// Grid (1024, 6): y<5 -> 1M-element tensors {x,Wq,Wk,Wv,Wo}; y==5 -> packed
// gate weights (Wa|We|Wt|Wg rows -> 64x1024), only blocks x<64 active.
// ---------------------------------------------------------------------------
__global__ __launch_bounds__(256) void split_all_kernel(
    const float* __restrict__ x, const float* __restrict__ Wq,
    const float* __restrict__ Wk, const float* __restrict__ Wv,
    const float* __restrict__ Wo, const float* __restrict__ Wa,
    const float* __restrict__ We, const float* __restrict__ Wt,
    const float* __restrict__ Wg,
    _Float16* __restrict__ xh, _Float16* __restrict__ xl,
    _Float16* __restrict__ Wqh, _Float16* __restrict__ Wql,
    _Float16* __restrict__ Wkh, _Float16* __restrict__ Wkl,
    _Float16* __restrict__ Wvh, _Float16* __restrict__ Wvl,
    _Float16* __restrict__ Woh, _Float16* __restrict__ Wol,
    _Float16* __restrict__ gWh, _Float16* __restrict__ gWl) {
  const int y = blockIdx.y;
  const int tid = threadIdx.x;
  if (y < 5) {
    const float* src = (y == 0 ? x : y == 1 ? Wq : y == 2 ? Wk : y == 3 ? Wv : Wo);
    _Float16* dh = (y == 0 ? xh : y == 1 ? Wqh : y == 2 ? Wkh : y == 3 ? Wvh : Woh);
    _Float16* dl = (y == 0 ? xl : y == 1 ? Wql : y == 2 ? Wkl : y == 3 ? Wvl : Wol);
    size_t i = ((size_t)blockIdx.x * 256 + tid) * 4;
    float4 v = *(const float4*)(src + i);
    half4 h, l;
#pragma unroll
    for (int j = 0; j < 4; ++j) { _Float16 hh, ll; split_f16((&v.x)[j], hh, ll); h[j] = hh; l[j] = ll; }
    *(half4*)(dh + i) = h;
    *(half4*)(dl + i) = l;
  } else {
    if (blockIdx.x >= 64) return;
    size_t i = ((size_t)blockIdx.x * 256 + tid) * 4;
    int gsel = (int)(i >> 14);
    int off = (int)(i & 16383);
    const float* src = (gsel == 0 ? Wa : gsel == 1 ? We : gsel == 2 ? Wt : Wg);
    float4 v = *(const float4*)(src + off);
    half4 h, l;
#pragma unroll
    for (int j = 0; j < 4; ++j) { _Float16 hh, ll; split_f16((&v.x)[j], hh, ll); h[j] = hh; l[j] = ll; }
    *(half4*)(gWh + i) = h;
    *(half4*)(gWl + i) = l;
  }
}

// ---------------------------------------------------------------------------
// Split-f16 MFMA GEMM core: 64x64 output tile, K=1024, O = A @ B^T.
// 4 waves, one 32x32 tile each; LDS planes (8KB each): Ah 0 / Al 8192 /
// Bh 16384 / Bl 24576, 64x64 f16 rows with XOR bank swizzle (pe geometry).
// ---------------------------------------------------------------------------
__device__ __forceinline__ void gemm64_core(const _Float16* __restrict__ Agh,
                                            const _Float16* __restrict__ Agl,
                                            const _Float16* __restrict__ Bgh,
                                            const _Float16* __restrict__ Bgl,
                                            int m0, int n0, int tid, char* LB,
                                            f32x16& accH, f32x16& accL) {
  const int lane = tid & 63, wv = tid >> 6;
  const int mb = (wv >> 1) << 5, nb = (wv & 1) << 5;
  const int lr = tid >> 2;             // staging row 0..63
  const int lch = (tid & 3) << 4;      // half col {0,16,32,48}
  const int cb = lch << 1;             // byte col
  const int wb0 = (lr << 7) + (cb ^ ((lr & 7) << 4));
  const int wb1 = (lr << 7) + ((cb + 16) ^ ((lr & 7) << 4));
  const _Float16* pah = Agh + (size_t)(m0 + lr) * Csz + lch;
  const _Float16* pal = Agl + (size_t)(m0 + lr) * Csz + lch;
  const _Float16* pbh = Bgh + (size_t)(n0 + lr) * Csz + lch;
  const _Float16* pbl = Bgl + (size_t)(n0 + lr) * Csz + lch;
  int ra_m[4], ra_n[4];
#pragma unroll
  for (int ks = 0; ks < 4; ++ks) {
    int rm = mb + (lane & 31), rn = nb + (lane & 31);
    int cB = (ks << 5) + ((lane >> 5) << 4);
    ra_m[ks] = (rm << 7) + (cB ^ ((rm & 7) << 4));
    ra_n[ks] = (rn << 7) + (cB ^ ((rn & 7) << 4));
  }
#pragma unroll
  for (int r = 0; r < 16; ++r) { accH[r] = 0.f; accL[r] = 0.f; }
  for (int k0 = 0; k0 < Csz; k0 += 64) {
    half8 vah0 = *(const half8*)(pah + k0), vah1 = *(const half8*)(pah + k0 + 8);
    half8 val0 = *(const half8*)(pal + k0), val1 = *(const half8*)(pal + k0 + 8);
    half8 vbh0 = *(const half8*)(pbh + k0), vbh1 = *(const half8*)(pbh + k0 + 8);
    half8 vbl0 = *(const half8*)(pbl + k0), vbl1 = *(const half8*)(pbl + k0 + 8);
    __syncthreads();
    *(half8*)(LB + wb0) = vah0;          *(half8*)(LB + wb1) = vah1;
    *(half8*)(LB + 8192 + wb0) = val0;   *(half8*)(LB + 8192 + wb1) = val1;
    *(half8*)(LB + 16384 + wb0) = vbh0;  *(half8*)(LB + 16384 + wb1) = vbh1;
    *(half8*)(LB + 24576 + wb0) = vbl0;  *(half8*)(LB + 24576 + wb1) = vbl1;
    __syncthreads();
    __builtin_amdgcn_s_setprio(1);
#pragma unroll
    for (int ks = 0; ks < 4; ++ks) {
      half8 ah = *(const half8*)(LB + ra_m[ks]);
      half8 al = *(const half8*)(LB + 8192 + ra_m[ks]);
      half8 bh = *(const half8*)(LB + 16384 + ra_n[ks]);
      half8 bl = *(const half8*)(LB + 24576 + ra_n[ks]);
      MFMA2(accH, accL, ah, al, bh, bl);
    }
    __builtin_amdgcn_s_setprio(0);
  }
}

// ---------------------------------------------------------------------------
// Fused QKV + gates GEMM via split-f16 MFMA. Grid (16, 49):
//   by in [0,48): mat = by>>4 -> qlin/klin/vlin, n0=(by&15)*64
//   by == 48   : 64 gate cols (4 mats x 16 heads) + sigmoid -> ga/ge/gt/gg
// ---------------------------------------------------------------------------
__global__ __launch_bounds__(256) void qkvg_mfma(
    const _Float16* __restrict__ xh, const _Float16* __restrict__ xl,
    const _Float16* __restrict__ Wqh, const _Float16* __restrict__ Wql,
    const _Float16* __restrict__ Wkh, const _Float16* __restrict__ Wkl,
    const _Float16* __restrict__ Wvh, const _Float16* __restrict__ Wvl,
    const _Float16* __restrict__ gWh, const _Float16* __restrict__ gWl,
    float* __restrict__ qlin, float* __restrict__ klin, float* __restrict__ vlin,
    float* __restrict__ ga, float* __restrict__ ge,
    float* __restrict__ gt, float* __restrict__ gg) {
  __shared__ __attribute__((aligned(16))) char LB[32768];
  const int tid = threadIdx.x;
  const int by = blockIdx.y;
  const int m0 = blockIdx.x << 6;
  const _Float16 *Bh, *Bl;
  int n0;
  if (by < 48) {
    const int mat = by >> 4;
    n0 = (by & 15) << 6;
    Bh = (mat == 0 ? Wqh : mat == 1 ? Wkh : Wvh);
    Bl = (mat == 0 ? Wql : mat == 1 ? Wkl : Wvl);
  } else {
    n0 = 0;
    Bh = gWh;
    Bl = gWl;
  }
  f32x16 accH, accL;
  gemm64_core(xh, xl, Bh, Bl, m0, n0, tid, LB, accH, accL);
  const int lane = tid & 63, wv = tid >> 6;
  const int mb = (wv >> 1) << 5, nb = (wv & 1) << 5;
  const int crow = (lane >> 5) << 2, ccol = lane & 31;
  if (by < 48) {
    const int mat = by >> 4;
    float* O = (mat == 0 ? qlin : mat == 1 ? klin : vlin);
#pragma unroll
    for (int r = 0; r < 16; ++r) {
      int row = mb + crow + (r & 3) + ((r >> 2) << 3);
      O[(size_t)(m0 + row) * Csz + n0 + nb + ccol] = accH[r] + accL[r] * INV_S;
    }
  } else {
    const int col = nb + ccol;
    const int gsel = col >> 4, h = col & 15;
    float* outp = (gsel == 0 ? ga : gsel == 1 ? ge : gsel == 2 ? gt : gg);
#pragma unroll
    for (int r = 0; r < 16; ++r) {
      int row = mb + crow + (r & 3) + ((r >> 2) << 3);
      float v = accH[r] + accL[r] * INV_S;
      outp[(size_t)(m0 + row) * Hsz + h] = 1.f / (1.f + expf(-v));
    }
  }
}

// ---------------------------------------------------------------------------
// Out-projection GEMM via split-f16 MFMA. Grid (16,16).
// ---------------------------------------------------------------------------
__global__ __launch_bounds__(256) void out_mfma(
    const _Float16* __restrict__ yh, const _Float16* __restrict__ yl,
    const _Float16* __restrict__ Woh, const _Float16* __restrict__ Wol,
    float* __restrict__ out) {
  __shared__ __attribute__((aligned(16))) char LB[32768];
  const int tid = threadIdx.x;
  const int m0 = blockIdx.x << 6, n0 = blockIdx.y << 6;
  f32x16 accH, accL;
  gemm64_core(yh, yl, Woh, Wol, m0, n0, tid, LB, accH, accL);
  const int lane = tid & 63, wv = tid >> 6;
  const int mb = (wv >> 1) << 5, nb = (wv & 1) << 5;
  const int crow = (lane >> 5) << 2, ccol = lane & 31;
#pragma unroll
  for (int r = 0; r < 16; ++r) {
    int row = mb + crow + (r & 3) + ((r >> 2) << 3);
    out[(size_t)(m0 + row) * Csz + n0 + nb + ccol] = accH[r] + accL[r] * INV_S;
  }
}

// ---------------------------------------------------------------------------
// Causal depthwise conv (K=4) + optional rms_norm/poly. Grid (B*T, 3).
// ---------------------------------------------------------------------------
__global__ __launch_bounds__(256) void conv3_kernel(const float* __restrict__ qlin,
                                                    const float* __restrict__ klin,
                                                    const float* __restrict__ vlin,
                                                    const float* __restrict__ cqw,
                                                    const float* __restrict__ ckw,
                                                    const float* __restrict__ cvw,
                                                    const float* __restrict__ cqb,
                                                    const float* __restrict__ ckb,
                                                    const float* __restrict__ cvb,
                                                    float* __restrict__ qp,
                                                    float* __restrict__ kp,
                                                    float* __restrict__ vp) {
  const int sel = blockIdx.y;
  const float* lin = (sel == 0 ? qlin : sel == 1 ? klin : vlin);
  const float* w = (sel == 0 ? cqw : sel == 1 ? ckw : cvw);
  const float* bias = (sel == 0 ? cqb : sel == 1 ? ckb : cvb);
  float* out = (sel == 0 ? qp : sel == 1 ? kp : vp);
  const int do_norm = (sel < 2);
  const int bt = blockIdx.x;
  const int b = bt >> 9, t = bt & 511;
  const int tid = threadIdx.x;
  const int c0 = tid << 2;
  float4 bv = *(const float4*)&bias[c0];
  float v0 = bv.x, v1 = bv.y, v2 = bv.z, v3 = bv.w;
  float4 w0 = *(const float4*)&w[(c0 + 0) * 4];
  float4 w1 = *(const float4*)&w[(c0 + 1) * 4];
  float4 w2 = *(const float4*)&w[(c0 + 2) * 4];
  float4 w3 = *(const float4*)&w[(c0 + 3) * 4];
  const float* base = lin + (size_t)b * Tsz * Csz + c0;
#pragma unroll
  for (int j = 0; j < 4; ++j) {
    int tt = t - 3 + j;
    if (tt < 0) continue;
    float4 xv = *(const float4*)(base + (size_t)tt * Csz);
    v0 += xv.x * (&w0.x)[j];
    v1 += xv.y * (&w1.x)[j];
    v2 += xv.z * (&w2.x)[j];
    v3 += xv.w * (&w3.x)[j];
  }
  if (do_norm) {
    float ss = v0 * v0 + v1 * v1 + v2 * v2 + v3 * v3;
    ss += __shfl_xor(ss, 1, 16);
    ss += __shfl_xor(ss, 2, 16);
    ss += __shfl_xor(ss, 4, 16);
    ss += __shfl_xor(ss, 8, 16);
    float scl = rsqrtf(ss * (1.f / 64.f) + 1e-6f);
    v0 *= scl; v1 *= scl; v2 *= scl; v3 *= scl;
    v0 += 0.5f * v0 * v0; v1 += 0.5f * v1 * v1; v2 += 0.5f * v2 * v2; v3 += 0.5f * v3 * v3;
  }
  float4 o = {v0, v1, v2, v3};
  *(float4*)(out + (size_t)bt * Csz + c0) = o;
}

// ---------------------------------------------------------------------------
// rms_norm for y -> split-f16 planes (feeds out_mfma)
// ---------------------------------------------------------------------------
__global__ __launch_bounds__(256) void rms_split_kernel(const float* __restrict__ in,
                                                        _Float16* __restrict__ yh,
                                                        _Float16* __restrict__ yl) {
  const int bt = blockIdx.x;
  const int tid = threadIdx.x;
  const int c0 = tid << 2;
  float4 xv = *(const float4*)(in + (size_t)bt * Csz + c0);
  float ss = xv.x * xv.x + xv.y * xv.y + xv.z * xv.z + xv.w * xv.w;
  ss += __shfl_xor(ss, 1, 16);
  ss += __shfl_xor(ss, 2, 16);
  ss += __shfl_xor(ss, 4, 16);
  ss += __shfl_xor(ss, 8, 16);
  float scl = rsqrtf(ss * (1.f / 64.f) + 1e-6f);
  half4 h, l;
#pragma unroll
  for (int j = 0; j < 4; ++j) {
    _Float16 hh, ll;
    split_f16((&xv.x)[j] * scl, hh, ll);
    h[j] = hh; l[j] = ll;
  }
  *(half4*)(yh + (size_t)bt * Csz + c0) = h;
  *(half4*)(yl + (size_t)bt * Csz + c0) = l;
}

// ---------------------------------------------------------------------------
// Standalone momentum scan (chunk 0 only).
// ---------------------------------------------------------------------------
__global__ __launch_bounds__(256) void mom_scan_kernel(const float* __restrict__ Mst,
                                                       const float* __restrict__ kp,
                                                       const float* __restrict__ vp,
                                                       const float* __restrict__ geta,
                                                       const float* __restrict__ gtheta,
                                                       const float* __restrict__ ggamma,
                                                       float* __restrict__ Sst,
                                                       float* __restrict__ chunkS, int ci) {
  __shared__ float Ml[4 * Dsz];
  __shared__ float errl[256];
  __shared__ float kkl[CSz * Dsz];
  __shared__ float gl[CSz], el[CSz], tl[CSz];
  const int blk = blockIdx.x;
  const int bh = blk >> 4, eb = blk & 15;
  const int b = bh >> 4, h = bh & 15;
  const int tid = threadIdx.x;
  Ml[tid & 255] = Mst[(size_t)bh * 4096 + eb * 4 * 64 + tid];
#pragma unroll
  for (int i = 0; i < 16; ++i) {
    int idx = i * 256 + tid;
    int t = idx >> 6, k = idx & 63;
    kkl[idx] = kp[(((size_t)b * Tsz + ci * CSz + t) * Hsz + h) * Dsz + k];
  }
  if (tid < CSz) {
    size_t gi = ((size_t)b * Tsz + ci * CSz + tid) * Hsz + h;
    gl[tid] = ggamma[gi];
    el[tid] = geta[gi];
    tl[tid] = gtheta[gi];
  }
  __syncthreads();
  {
    const int tt = tid >> 2, vl = tid & 3;
    float acc = 0.f;
#pragma unroll
    for (int i = 0; i < 16; ++i) {
      float4 m4 = *(const float4*)&Ml[vl * 64 + i * 4];
      float4 k4 = *(const float4*)&kkl[tt * 64 + i * 4];
      acc += m4.x * k4.x + m4.y * k4.y + m4.z * k4.z + m4.w * k4.w;
    }
    float vv = vp[(((size_t)b * Tsz + ci * CSz + tt) * Hsz + h) * Dsz + eb * 4 + vl];
    errl[tt * 4 + vl] = acc - vv;
  }
  __syncthreads();
  const int e = eb * 256 + tid;
  const int vloc = tid >> 6;
  const int k = tid & 63;
  float S = Sst[(size_t)bh * 4096 + e];
  float ring[OW];
  float wsum = 0.f;
  float* outp = chunkS + (size_t)bh * CSz * 4096 + e;
#pragma unroll
  for (int t = 0; t < CSz; ++t) {
    float u = 2.f * errl[t * 4 + vloc] * kkl[t * 64 + k];
    float val = gl[t] * u;
    wsum += val;
    if (t >= OW) wsum -= ring[t & (OW - 1)];
    ring[t & (OW - 1)] = val;
    S = tl[t] * S - el[t] * wsum;
    outp[(size_t)t * 4096] = S;
  }
  Sst[(size_t)bh * 4096 + e] = S;
}

// ---------------------------------------------------------------------------
// Fused: memory scan + read (chunk ci), then momentum scan (chunk ci+1).
// ---------------------------------------------------------------------------
__global__ __launch_bounds__(256) void fused_scan_kernel(float* __restrict__ chunkS,
                                                         const float* __restrict__ qp,
                                                         const float* __restrict__ kp,
                                                         const float* __restrict__ vp,
                                                         const float* __restrict__ galpha,
                                                         const float* __restrict__ geta,
                                                         const float* __restrict__ gtheta,
                                                         const float* __restrict__ ggamma,
                                                         float* __restrict__ Mst,
                                                         float* __restrict__ Sst,
                                                         float* __restrict__ ybuf,
                                                         int ci, int do_next) {
  __shared__ float buf[CSz * Dsz];  // ql (mem phase) then kkl (mom phase)
  __shared__ float al[CSz];
  __shared__ float Ml[4 * Dsz];
  __shared__ float errl[256];
  __shared__ float gl[CSz], el[CSz], tl[CSz];
  const int blk = blockIdx.x;
  const int bh = blk >> 4, eb = blk & 15;
  const int b = bh >> 4, h = bh & 15;
  const int tid = threadIdx.x;
  const int w = tid >> 6, lane = tid & 63;
  const int v = eb * 4 + w, k = lane;
  // ---- mem phase (chunk ci) ----
  for (int i = tid; i < CSz * Dsz; i += 256) {
    int t = i >> 6, kk = i & 63;
    buf[i] = qp[(((size_t)b * Tsz + ci * CSz + t) * Hsz + h) * Dsz + kk];
  }
  if (tid < CSz) al[tid] = galpha[((size_t)b * Tsz + ci * CSz + tid) * Hsz + h];
  __syncthreads();
  float m = Mst[(size_t)bh * 4096 + v * 64 + k];
  const float* Xo = chunkS + (size_t)bh * CSz * 4096;
  for (int t = 0; t < CSz; ++t) {
    m = al[t] * m + Xo[(size_t)t * 4096 + v * 64 + k];
    float p = m * buf[t * 64 + k];
#pragma unroll
    for (int off = 32; off; off >>= 1) p += __shfl_xor(p, off, 64);
    if (lane == 0) ybuf[(((size_t)b * Tsz + ci * CSz + t) * Hsz + h) * Dsz + v] = p;
  }
  Mst[(size_t)bh * 4096 + v * 64 + k] = m;
  if (!do_next) return;
  Ml[w * 64 + k] = m;
  __syncthreads();  // ql reads done (buf reusable); Ml visible
  // ---- mom phase (chunk ci+1) ----
  const int cj = ci + 1;
#pragma unroll
  for (int i = 0; i < 16; ++i) {
    int idx = i * 256 + tid;
    int t = idx >> 6, kk = idx & 63;
    buf[idx] = kp[(((size_t)b * Tsz + cj * CSz + t) * Hsz + h) * Dsz + kk];
  }
  if (tid < CSz) {
    size_t gi = ((size_t)b * Tsz + cj * CSz + tid) * Hsz + h;
    gl[tid] = ggamma[gi];
    el[tid] = geta[gi];
    tl[tid] = gtheta[gi];
  }
  __syncthreads();
  {
    const int tt = tid >> 2, vl = tid & 3;
    float acc = 0.f;
#pragma unroll
    for (int i = 0; i < 16; ++i) {
      float4 m4 = *(const float4*)&Ml[vl * 64 + i * 4];
      float4 k4 = *(const float4*)&buf[tt * 64 + i * 4];
      acc += m4.x * k4.x + m4.y * k4.y + m4.z * k4.z + m4.w * k4.w;
    }
    float vv = vp[(((size_t)b * Tsz + cj * CSz + tt) * Hsz + h) * Dsz + eb * 4 + vl];
    errl[tt * 4 + vl] = acc - vv;
  }
  __syncthreads();
  const int e = eb * 256 + tid;
  const int vloc = tid >> 6;
  float S = Sst[(size_t)bh * 4096 + e];
  float ring[OW];
  float wsum = 0.f;
  float* outp = chunkS + (size_t)bh * CSz * 4096 + e;
#pragma unroll
  for (int t = 0; t < CSz; ++t) {
    float u = 2.f * errl[t * 4 + vloc] * buf[t * 64 + k];
    float val = gl[t] * u;
    wsum += val;
    if (t >= OW) wsum -= ring[t & (OW - 1)];
    ring[t & (OW - 1)] = val;
    S = tl[t] * S - el[t] * wsum;
    outp[(size_t)t * 4096] = S;
  }
  Sst[(size_t)bh * 4096 + e] = S;
}

// ---------------------------------------------------------------------------
// B3: Polar Express via scaled split-f16 MFMA, re-associated dataflow:
//   A = X X^T ; W = A X ; U = A W ; X' = a X + b W + c U
// ---------------------------------------------------------------------------
__global__ __launch_bounds__(256, 3) void pe_mfma_kernel(float* __restrict__ chunkS) {
  __shared__ __attribute__((aligned(16))) _Float16 PL[6 * 4096];
  __shared__ float red[4];
  const int tid = threadIdx.x;
  const int lane = tid & 63;
  const int wv = tid >> 6;
  float* G = chunkS + (size_t)blockIdx.x * 4096;
  constexpr int PLO = 8192;   // hi->lo plane byte distance
  constexpr int PT = 16384;   // X^T plane pair (fixed role)
  char* const LB = (char*)PL;

  const int mb = (wv >> 1) << 5;
  const int nb = (wv & 1) << 5;
  const int crow = ((lane >> 5) << 2);
  const int ccol = lane & 31;

  int ra_m[4], ra_n[4];
#pragma unroll
  for (int ks = 0; ks < 4; ++ks) {
    int rm = mb + (lane & 31), rn = nb + (lane & 31);
    int cB = (ks << 5) + ((lane >> 5) << 4);
    ra_m[ks] = (rm << 7) + (cB ^ ((rm & 7) << 4));
    ra_n[ks] = (rn << 7) + (cB ^ ((rn & 7) << 4));
  }
  int sa[4];
  {
    const int base = (nb + ccol) << 7;
    const int sw = ((nb + ccol) & 7) << 4;
    const int c2 = crow << 1;
#pragma unroll
    for (int g = 0; g < 4; ++g) sa[g] = base + ((((mb + 8 * g) << 1) ^ sw) + c2);
  }
  int rowa[4];
#pragma unroll
  for (int j = 0; j < 4; ++j) {
    int rr = mb + crow + j;
    rowa[j] = (rr << 7) + (((nb + ccol) << 1) ^ ((rr & 7) << 4));
  }

#define LDF(PB, RA, ks) (*(const half8*)(LB + (PB) + (RA)[ks]))

  auto STS = [&](int PB, const _Float16* hs, const _Float16* ls) {
#pragma unroll
    for (int g = 0; g < 4; ++g) {
      half4 hv, lv;
#pragma unroll
      for (int j = 0; j < 4; ++j) { hv[j] = hs[g * 4 + j]; lv[j] = ls[g * 4 + j]; }
      *(half4*)(LB + PB + sa[g]) = hv;
      *(half4*)(LB + PB + PLO + sa[g]) = lv;
    }
  };
  auto STR = [&](int PB, const _Float16* hs, const _Float16* ls) {
#pragma unroll
    for (int r = 0; r < 16; ++r) {
      int off = rowa[r & 3] + ((r >> 2) << 10);
      *(_Float16*)(LB + PB + off) = hs[r];
      *(_Float16*)(LB + PB + PLO + off) = ls[r];
    }
  };

  float Xval[16];
  float ss = 0.f;
#pragma unroll
  for (int r = 0; r < 16; ++r) {
    int rr = mb + crow + (r & 3) + ((r >> 2) << 3);
    float xv = G[rr * 64 + nb + ccol];
    Xval[r] = xv;
    ss += xv * xv;
  }
#pragma unroll
  for (int off = 32; off; off >>= 1) ss += __shfl_xor(ss, off, 64);
  if (lane == 0) red[wv] = ss;
  __syncthreads();
  float tot = red[0] + red[1] + red[2] + red[3];
  float scale = 1.f / ((sqrtf(tot) + 1e-7f) * 1.01f);

  {
    _Float16 hs[16], ls[16];
#pragma unroll
    for (int r = 0; r < 16; ++r) {
      Xval[r] *= scale;
      split_f16(Xval[r], hs[r], ls[r]);
    }
    STR(0, hs, ls);
    STS(PT, hs, ls);
  }

  auto iter = [&](float ca, float cb, float cc, int PXB, int PAB, bool last) {
    __syncthreads();  // B_a
    if (wv != 2) {
      f32x16 accH, accL;
#pragma unroll
      for (int r = 0; r < 16; ++r) { accH[r] = 0.f; accL[r] = 0.f; }
      __builtin_amdgcn_s_setprio(1);
#pragma unroll
      for (int ks = 0; ks < 4; ++ks) {
        half8 ah = LDF(PXB, ra_m, ks), al = LDF(PXB + PLO, ra_m, ks);
        half8 bh, bl;
        if (mb != nb) { bh = LDF(PXB, ra_n, ks); bl = LDF(PXB + PLO, ra_n, ks); }
        else { bh = ah; bl = al; }
        MFMA2(accH, accL, ah, al, bh, bl);
      }
      __builtin_amdgcn_s_setprio(0);
      _Float16 hs[16], ls[16];
#pragma unroll
      for (int r = 0; r < 16; ++r) split_f16(accH[r] + accL[r] * INV_S, hs[r], ls[r]);
      STS(PAB, hs, ls);
      if (wv == 1) STR(PAB, hs, ls);
    }
    __syncthreads();  // B_b
    half8 fah[4], fal[4];
    f32x16 acWH, acWL;
#pragma unroll
    for (int r = 0; r < 16; ++r) { acWH[r] = 0.f; acWL[r] = 0.f; }
    __builtin_amdgcn_s_setprio(1);
#pragma unroll
    for (int ks = 0; ks < 4; ++ks) {
      fah[ks] = LDF(PAB, ra_m, ks);
      fal[ks] = LDF(PAB + PLO, ra_m, ks);
      half8 bh = LDF(PT, ra_n, ks), bl = LDF(PT + PLO, ra_n, ks);
      MFMA2(acWH, acWL, fah[ks], fal[ks], bh, bl);
    }
    __builtin_amdgcn_s_setprio(0);
    float Wval[16];
    {
      _Float16 hs[16], ls[16];
#pragma unroll
      for (int r = 0; r < 16; ++r) {
        Wval[r] = acWH[r] + acWL[r] * INV_S;
        split_f16(Wval[r], hs[r], ls[r]);
      }
      STS(PXB, hs, ls);
    }
    __syncthreads();  // B_c
    f32x16 acUH, acUL;
#pragma unroll
    for (int r = 0; r < 16; ++r) { acUH[r] = 0.f; acUL[r] = 0.f; }
    __builtin_amdgcn_s_setprio(1);
#pragma unroll
    for (int ks = 0; ks < 4; ++ks) {
      half8 bh = LDF(PXB, ra_n, ks), bl = LDF(PXB + PLO, ra_n, ks);
      MFMA2(acUH, acUL, fah[ks], fal[ks], bh, bl);
    }
    __builtin_amdgcn_s_setprio(0);
    if (!last) {
      _Float16 hs[16], ls[16];
#pragma unroll
      for (int r = 0; r < 16; ++r) {
        float xn = ca * Xval[r] + cb * Wval[r] + cc * (acUH[r] + acUL[r] * INV_S);
        Xval[r] = xn;
        split_f16(xn, hs[r], ls[r]);
      }
      STR(PAB, hs, ls);
      STS(PT, hs, ls);
    } else {
#pragma unroll
      for (int r = 0; r < 16; ++r) {
        int rr = mb + crow + (r & 3) + ((r >> 2) << 3);
        G[rr * 64 + nb + ccol] = ca * Xval[r] + cb * Wval[r] + cc * (acUH[r] + acUL[r] * INV_S);
      }
    }
  };

  iter(8.28721201814563f, -23.595886519098837f, 17.300387312530933f, 0, 32768, false);
  iter(4.107059111542203f, -2.9478499167379106f, 0.5448431082926601f, 32768, 0, false);
  iter(3.9486908534822946f, -2.908902115962949f, 0.5518191394370137f, 0, 32768, false);
  iter(3.3184196573706015f, -2.488488024314874f, 0.51004894012372f, 32768, 0, false);
  iter(2.300652019954817f, -1.6689039845747493f, 0.4188073119525673f, 0, 32768, true);
}

// ---------------------------------------------------------------------------
extern "C" void kernel_launch(void* const* d_in, const int* in_sizes, int n_in,
                              void* d_out, int out_size, void* d_ws, size_t ws_size,
                              hipStream_t stream) {
  (void)in_sizes; (void)n_in; (void)out_size; (void)ws_size;
  const float* x   = (const float*)d_in[0];
  const float* Wq  = (const float*)d_in[1];
  const float* Wk  = (const float*)d_in[2];
  const float* Wv  = (const float*)d_in[3];
  const float* Wo  = (const float*)d_in[4];
  const float* cqw = (const float*)d_in[5];
  const float* cqb = (const float*)d_in[6];
  const float* ckw = (const float*)d_in[7];
  const float* ckb = (const float*)d_in[8];
  const float* cvw = (const float*)d_in[9];
  const float* cvb = (const float*)d_in[10];
  const float* Wa  = (const float*)d_in[11];
  const float* We  = (const float*)d_in[12];
  const float* Wt  = (const float*)d_in[13];
  const float* Wg  = (const float*)d_in[14];
  float* out = (float*)d_out;

  float* p = (float*)d_ws;
  const size_t NBTC = (size_t)Bsz * Tsz * Csz;   // 1M
  const size_t NBTH = (size_t)Bsz * Tsz * Hsz;
  const size_t NMAT = (size_t)Bsz * Hsz * Dsz * Dsz;
  const size_t NWW = (size_t)Csz * Csz;          // 1M
  float* qlin = p; p += NBTC;
  float* klin = p; p += NBTC;
  float* vlin = p; p += NBTC;
  float* qp   = p; p += NBTC;
  float* kp   = p; p += NBTC;
  float* vp   = p; p += NBTC;
  float* ga   = p; p += NBTH;
  float* ge   = p; p += NBTH;
  float* gt   = p; p += NBTH;
  float* gg   = p; p += NBTH;
  float* Mst  = p; p += NMAT;
  float* Sst  = p; p += NMAT;
  float* chS  = p; p += (size_t)Bsz * Hsz * CSz * Dsz * Dsz;
  float* ybuf = p; p += NBTC;
  // f16 split planes
  _Float16* hp = (_Float16*)p;
  _Float16* xh  = hp; hp += NBTC;
  _Float16* xl  = hp; hp += NBTC;
  _Float16* Wqh = hp; hp += NWW;
  _Float16* Wql = hp; hp += NWW;
  _Float16* Wkh = hp; hp += NWW;
  _Float16* Wkl = hp; hp += NWW;
  _Float16* Wvh = hp; hp += NWW;
  _Float16* Wvl = hp; hp += NWW;
  _Float16* Woh = hp; hp += NWW;
  _Float16* Wol = hp; hp += NWW;
  _Float16* gWh = hp; hp += (size_t)64 * Csz;
  _Float16* gWl = hp; hp += (size_t)64 * Csz;
  _Float16* yh  = hp; hp += NBTC;
  _Float16* yl  = hp; hp += NBTC;

  hipMemsetAsync(Mst, 0, NMAT * sizeof(float), stream);
  hipMemsetAsync(Sst, 0, NMAT * sizeof(float), stream);

  split_all_kernel<<<dim3(1024, 6), 256, 0, stream>>>(
      x, Wq, Wk, Wv, Wo, Wa, We, Wt, Wg,
      xh, xl, Wqh, Wql, Wkh, Wkl, Wvh, Wvl, Woh, Wol, gWh, gWl);
  qkvg_mfma<<<dim3(16, 49), 256, 0, stream>>>(
      xh, xl, Wqh, Wql, Wkh, Wkl, Wvh, Wvl, gWh, gWl,
      qlin, klin, vlin, ga, ge, gt, gg);
  conv3_kernel<<<dim3(Bsz * Tsz, 3), 256, 0, stream>>>(qlin, klin, vlin, cqw, ckw, cvw,
                                                       cqb, ckb, cvb, qp, kp, vp);

  mom_scan_kernel<<<Bsz * Hsz * 16, 256, 0, stream>>>(Mst, kp, vp, ge, gt, gg, Sst, chS, 0);
  for (int ci = 0; ci < NCHUNK; ++ci) {
    pe_mfma_kernel<<<Bsz * Hsz * CSz, 256, 0, stream>>>(chS);
    fused_scan_kernel<<<Bsz * Hsz * 16, 256, 0, stream>>>(chS, qp, kp, vp, ga, ge, gt, gg,
                                                          Mst, Sst, ybuf, ci,
                                                          ci < NCHUNK - 1 ? 1 : 0);
  }

  rms_split_kernel<<<Bsz * Tsz, 256, 0, stream>>>(ybuf, yh, yl);
  out_mfma<<<dim3(16, 16), 256, 0, stream>>>(yh, yl, Woh, Wol, out);
}

// Round 5
// 871.829 us; speedup vs baseline: 1.4603x; 1.1587x over previous
//
#include <hip/hip_runtime.h>

// Problem constants
constexpr int Bsz = 2, Tsz = 512, Csz = 1024, Hsz = 16, Dsz = 64, CSz = 64;
constexpr int NCHUNK = 8, OW = 8;

typedef __attribute__((ext_vector_type(8))) _Float16 half8;
typedef __attribute__((ext_vector_type(4))) _Float16 half4;
typedef __attribute__((ext_vector_type(16))) float f32x16;

constexpr float INV_S = 1.0f / 2048.0f;

// fp32 v ~= hi + lo/2048 (f16 pair). Proven precision-adequate by pe kernel.
__device__ __forceinline__ void split_f16(float v, _Float16& hi, _Float16& lo) {
  _Float16 h = (_Float16)v;
  float r = v - (float)h;
  hi = h;
  lo = (_Float16)(r * 2048.0f);
}

#define MFMA2(accH, accL, ah, al, bh, bl)                                     \
  accH = __builtin_amdgcn_mfma_f32_32x32x16_f16(ah, bh, accH, 0, 0, 0);       \
  accL = __builtin_amdgcn_mfma_f32_32x32x16_f16(ah, bl, accL, 0, 0, 0);       \
  accL = __builtin_amdgcn_mfma_f32_32x32x16_f16(al, bh, accL, 0, 0, 0);

// XCD-affinity decode: launched bid -> (bh, idx) with XCD(bid)=bid%8 == bh%8.
// bid = idx*32 + (bh>>3)*8 + (bh&7); bijective for bh in [0,32), idx in [0,IDX).
__device__ __forceinline__ void xcd_decode(int bid, int& bh, int& idx) {
  bh = (((bid >> 3) & 3) << 3) + (bid & 7);
  idx = bid >> 5;
}

// ---------------------------------------------------------------------------
// One-time fp32 -> (hi,lo) f16 plane conversion.
// Grid (1024, 6): y<5 -> 1M-element tensors {x,Wq,Wk,Wv,Wo}; y==5 -> packed
// gate weights (Wa|We|Wt|Wg rows -> 64x1024), only blocks x<64 active.
// ---------------------------------------------------------------------------
__global__ __launch_bounds__(256) void split_all_kernel(
    const float* __restrict__ x, const float* __restrict__ Wq,
    const float* __restrict__ Wk, const float* __restrict__ Wv,
    const float* __restrict__ Wo, const float* __restrict__ Wa,
    const float* __restrict__ We, const float* __restrict__ Wt,
    const float* __restrict__ Wg,
    _Float16* __restrict__ xh, _Float16* __restrict__ xl,
    _Float16* __restrict__ Wqh, _Float16* __restrict__ Wql,
    _Float16* __restrict__ Wkh, _Float16* __restrict__ Wkl,
    _Float16* __restrict__ Wvh, _Float16* __restrict__ Wvl,
    _Float16* __restrict__ Woh, _Float16* __restrict__ Wol,
    _Float16* __restrict__ gWh, _Float16* __restrict__ gWl) {
  const int y = blockIdx.y;
  const int tid = threadIdx.x;
  if (y < 5) {
    const float* src = (y == 0 ? x : y == 1 ? Wq : y == 2 ? Wk : y == 3 ? Wv : Wo);
    _Float16* dh = (y == 0 ? xh : y == 1 ? Wqh : y == 2 ? Wkh : y == 3 ? Wvh : Woh);
    _Float16* dl = (y == 0 ? xl : y == 1 ? Wql : y == 2 ? Wkl : y == 3 ? Wvl : Wol);
    size_t i = ((size_t)blockIdx.x * 256 + tid) * 4;
    float4 v = *(const float4*)(src + i);
    half4 h, l;
#pragma unroll
    for (int j = 0; j < 4; ++j) { _Float16 hh, ll; split_f16((&v.x)[j], hh, ll); h[j] = hh; l[j] = ll; }
    *(half4*)(dh + i) = h;
    *(half4*)(dl + i) = l;
  } else {
    if (blockIdx.x >= 64) return;
    size_t i = ((size_t)blockIdx.x * 256 + tid) * 4;
    int gsel = (int)(i >> 14);
    int off = (int)(i & 16383);
    const float* src = (gsel == 0 ? Wa : gsel == 1 ? We : gsel == 2 ? Wt : Wg);
    float4 v = *(const float4*)(src + off);
    half4 h, l;
#pragma unroll
    for (int j = 0; j < 4; ++j) { _Float16 hh, ll; split_f16((&v.x)[j], hh, ll); h[j] = hh; l[j] = ll; }
    *(half4*)(gWh + i) = h;
    *(half4*)(gWl + i) = l;
  }
}

// ---------------------------------------------------------------------------
// Split-f16 MFMA GEMM core: 64x64 output tile, K=1024, O = A @ B^T.
// ---------------------------------------------------------------------------
__device__ __forceinline__ void gemm64_core(const _Float16* __restrict__ Agh,
                                            const _Float16* __restrict__ Agl,
                                            const _Float16* __restrict__ Bgh,
                                            const _Float16* __restrict__ Bgl,
                                            int m0, int n0, int tid, char* LB,
                                            f32x16& accH, f32x16& accL) {
  const int lane = tid & 63, wv = tid >> 6;
  const int mb = (wv >> 1) << 5, nb = (wv & 1) << 5;
  const int lr = tid >> 2;             // staging row 0..63
  const int lch = (tid & 3) << 4;      // half col {0,16,32,48}
  const int cb = lch << 1;             // byte col
  const int wb0 = (lr << 7) + (cb ^ ((lr & 7) << 4));
  const int wb1 = (lr << 7) + ((cb + 16) ^ ((lr & 7) << 4));
  const _Float16* pah = Agh + (size_t)(m0 + lr) * Csz + lch;
  const _Float16* pal = Agl + (size_t)(m0 + lr) * Csz + lch;
  const _Float16* pbh = Bgh + (size_t)(n0 + lr) * Csz + lch;
  const _Float16* pbl = Bgl + (size_t)(n0 + lr) * Csz + lch;
  int ra_m[4], ra_n[4];
#pragma unroll
  for (int ks = 0; ks < 4; ++ks) {
    int rm = mb + (lane & 31), rn = nb + (lane & 31);
    int cB = (ks << 5) + ((lane >> 5) << 4);
    ra_m[ks] = (rm << 7) + (cB ^ ((rm & 7) << 4));
    ra_n[ks] = (rn << 7) + (cB ^ ((rn & 7) << 4));
  }
#pragma unroll
  for (int r = 0; r < 16; ++r) { accH[r] = 0.f; accL[r] = 0.f; }
  for (int k0 = 0; k0 < Csz; k0 += 64) {
    half8 vah0 = *(const half8*)(pah + k0), vah1 = *(const half8*)(pah + k0 + 8);
    half8 val0 = *(const half8*)(pal + k0), val1 = *(const half8*)(pal + k0 + 8);
    half8 vbh0 = *(const half8*)(pbh + k0), vbh1 = *(const half8*)(pbh + k0 + 8);
    half8 vbl0 = *(const half8*)(pbl + k0), vbl1 = *(const half8*)(pbl + k0 + 8);
    __syncthreads();
    *(half8*)(LB + wb0) = vah0;          *(half8*)(LB + wb1) = vah1;
    *(half8*)(LB + 8192 + wb0) = val0;   *(half8*)(LB + 8192 + wb1) = val1;
    *(half8*)(LB + 16384 + wb0) = vbh0;  *(half8*)(LB + 16384 + wb1) = vbh1;
    *(half8*)(LB + 24576 + wb0) = vbl0;  *(half8*)(LB + 24576 + wb1) = vbl1;
    __syncthreads();
    __builtin_amdgcn_s_setprio(1);
#pragma unroll
    for (int ks = 0; ks < 4; ++ks) {
      half8 ah = *(const half8*)(LB + ra_m[ks]);
      half8 al = *(const half8*)(LB + 8192 + ra_m[ks]);
      half8 bh = *(const half8*)(LB + 16384 + ra_n[ks]);
      half8 bl = *(const half8*)(LB + 24576 + ra_n[ks]);
      MFMA2(accH, accL, ah, al, bh, bl);
    }
    __builtin_amdgcn_s_setprio(0);
  }
}

// ---------------------------------------------------------------------------
// Fused QKV + gates GEMM via split-f16 MFMA. Grid (16, 49).
// ---------------------------------------------------------------------------
__global__ __launch_bounds__(256) void qkvg_mfma(
    const _Float16* __restrict__ xh, const _Float16* __restrict__ xl,
    const _Float16* __restrict__ Wqh, const _Float16* __restrict__ Wql,
    const _Float16* __restrict__ Wkh, const _Float16* __restrict__ Wkl,
    const _Float16* __restrict__ Wvh, const _Float16* __restrict__ Wvl,
    const _Float16* __restrict__ gWh, const _Float16* __restrict__ gWl,
    float* __restrict__ qlin, float* __restrict__ klin, float* __restrict__ vlin,
    float* __restrict__ ga, float* __restrict__ ge,
    float* __restrict__ gt, float* __restrict__ gg) {
  __shared__ __attribute__((aligned(16))) char LB[32768];
  const int tid = threadIdx.x;
  const int by = blockIdx.y;
  const int m0 = blockIdx.x << 6;
  const _Float16 *Bh, *Bl;
  int n0;
  if (by < 48) {
    const int mat = by >> 4;
    n0 = (by & 15) << 6;
    Bh = (mat == 0 ? Wqh : mat == 1 ? Wkh : Wvh);
    Bl = (mat == 0 ? Wql : mat == 1 ? Wkl : Wvl);
  } else {
    n0 = 0;
    Bh = gWh;
    Bl = gWl;
  }
  f32x16 accH, accL;
  gemm64_core(xh, xl, Bh, Bl, m0, n0, tid, LB, accH, accL);
  const int lane = tid & 63, wv = tid >> 6;
  const int mb = (wv >> 1) << 5, nb = (wv & 1) << 5;
  const int crow = (lane >> 5) << 2, ccol = lane & 31;
  if (by < 48) {
    const int mat = by >> 4;
    float* O = (mat == 0 ? qlin : mat == 1 ? klin : vlin);
#pragma unroll
    for (int r = 0; r < 16; ++r) {
      int row = mb + crow + (r & 3) + ((r >> 2) << 3);
      O[(size_t)(m0 + row) * Csz + n0 + nb + ccol] = accH[r] + accL[r] * INV_S;
    }
  } else {
    const int col = nb + ccol;
    const int gsel = col >> 4, h = col & 15;
    float* outp = (gsel == 0 ? ga : gsel == 1 ? ge : gsel == 2 ? gt : gg);
#pragma unroll
    for (int r = 0; r < 16; ++r) {
      int row = mb + crow + (r & 3) + ((r >> 2) << 3);
      float v = accH[r] + accL[r] * INV_S;
      outp[(size_t)(m0 + row) * Hsz + h] = 1.f / (1.f + expf(-v));
    }
  }
}

// ---------------------------------------------------------------------------
// Out-projection GEMM via split-f16 MFMA. Grid (16,16).
// ---------------------------------------------------------------------------
__global__ __launch_bounds__(256) void out_mfma(
    const _Float16* __restrict__ yh, const _Float16* __restrict__ yl,
    const _Float16* __restrict__ Woh, const _Float16* __restrict__ Wol,
    float* __restrict__ out) {
  __shared__ __attribute__((aligned(16))) char LB[32768];
  const int tid = threadIdx.x;
  const int m0 = blockIdx.x << 6, n0 = blockIdx.y << 6;
  f32x16 accH, accL;
  gemm64_core(yh, yl, Woh, Wol, m0, n0, tid, LB, accH, accL);
  const int lane = tid & 63, wv = tid >> 6;
  const int mb = (wv >> 1) << 5, nb = (wv & 1) << 5;
  const int crow = (lane >> 5) << 2, ccol = lane & 31;
#pragma unroll
  for (int r = 0; r < 16; ++r) {
    int row = mb + crow + (r & 3) + ((r >> 2) << 3);
    out[(size_t)(m0 + row) * Csz + n0 + nb + ccol] = accH[r] + accL[r] * INV_S;
  }
}

// ---------------------------------------------------------------------------
// Causal depthwise conv (K=4) + optional rms_norm/poly. Grid (B*T, 3).
// ---------------------------------------------------------------------------
__global__ __launch_bounds__(256) void conv3_kernel(const float* __restrict__ qlin,
                                                    const float* __restrict__ klin,
                                                    const float* __restrict__ vlin,
                                                    const float* __restrict__ cqw,
                                                    const float* __restrict__ ckw,
                                                    const float* __restrict__ cvw,
                                                    const float* __restrict__ cqb,
                                                    const float* __restrict__ ckb,
                                                    const float* __restrict__ cvb,
                                                    float* __restrict__ qp,
                                                    float* __restrict__ kp,
                                                    float* __restrict__ vp) {
  const int sel = blockIdx.y;
  const float* lin = (sel == 0 ? qlin : sel == 1 ? klin : vlin);
  const float* w = (sel == 0 ? cqw : sel == 1 ? ckw : cvw);
  const float* bias = (sel == 0 ? cqb : sel == 1 ? ckb : cvb);
  float* out = (sel == 0 ? qp : sel == 1 ? kp : vp);
  const int do_norm = (sel < 2);
  const int bt = blockIdx.x;
  const int b = bt >> 9, t = bt & 511;
  const int tid = threadIdx.x;
  const int c0 = tid << 2;
  float4 bv = *(const float4*)&bias[c0];
  float v0 = bv.x, v1 = bv.y, v2 = bv.z, v3 = bv.w;
  float4 w0 = *(const float4*)&w[(c0 + 0) * 4];
  float4 w1 = *(const float4*)&w[(c0 + 1) * 4];
  float4 w2 = *(const float4*)&w[(c0 + 2) * 4];
  float4 w3 = *(const float4*)&w[(c0 + 3) * 4];
  const float* base = lin + (size_t)b * Tsz * Csz + c0;
#pragma unroll
  for (int j = 0; j < 4; ++j) {
    int tt = t - 3 + j;
    if (tt < 0) continue;
    float4 xv = *(const float4*)(base + (size_t)tt * Csz);
    v0 += xv.x * (&w0.x)[j];
    v1 += xv.y * (&w1.x)[j];
    v2 += xv.z * (&w2.x)[j];
    v3 += xv.w * (&w3.x)[j];
  }
  if (do_norm) {
    float ss = v0 * v0 + v1 * v1 + v2 * v2 + v3 * v3;
    ss += __shfl_xor(ss, 1, 16);
    ss += __shfl_xor(ss, 2, 16);
    ss += __shfl_xor(ss, 4, 16);
    ss += __shfl_xor(ss, 8, 16);
    float scl = rsqrtf(ss * (1.f / 64.f) + 1e-6f);
    v0 *= scl; v1 *= scl; v2 *= scl; v3 *= scl;
    v0 += 0.5f * v0 * v0; v1 += 0.5f * v1 * v1; v2 += 0.5f * v2 * v2; v3 += 0.5f * v3 * v3;
  }
  float4 o = {v0, v1, v2, v3};
  *(float4*)(out + (size_t)bt * Csz + c0) = o;
}

// ---------------------------------------------------------------------------
// rms_norm for y -> split-f16 planes (feeds out_mfma)
// ---------------------------------------------------------------------------
__global__ __launch_bounds__(256) void rms_split_kernel(const float* __restrict__ in,
                                                        _Float16* __restrict__ yh,
                                                        _Float16* __restrict__ yl) {
  const int bt = blockIdx.x;
  const int tid = threadIdx.x;
  const int c0 = tid << 2;
  float4 xv = *(const float4*)(in + (size_t)bt * Csz + c0);
  float ss = xv.x * xv.x + xv.y * xv.y + xv.z * xv.z + xv.w * xv.w;
  ss += __shfl_xor(ss, 1, 16);
  ss += __shfl_xor(ss, 2, 16);
  ss += __shfl_xor(ss, 4, 16);
  ss += __shfl_xor(ss, 8, 16);
  float scl = rsqrtf(ss * (1.f / 64.f) + 1e-6f);
  half4 h, l;
#pragma unroll
  for (int j = 0; j < 4; ++j) {
    _Float16 hh, ll;
    split_f16((&xv.x)[j] * scl, hh, ll);
    h[j] = hh; l[j] = ll;
  }
  *(half4*)(yh + (size_t)bt * Csz + c0) = h;
  *(half4*)(yl + (size_t)bt * Csz + c0) = l;
}

// ---------------------------------------------------------------------------
// Standalone momentum scan (chunk 0 only). XCD-affinity remapped blockIdx.
// ---------------------------------------------------------------------------
__global__ __launch_bounds__(256) void mom_scan_kernel(const float* __restrict__ Mst,
                                                       const float* __restrict__ kp,
                                                       const float* __restrict__ vp,
                                                       const float* __restrict__ geta,
                                                       const float* __restrict__ gtheta,
                                                       const float* __restrict__ ggamma,
                                                       float* __restrict__ Sst,
                                                       float* __restrict__ chunkS, int ci) {
  __shared__ float Ml[4 * Dsz];
  __shared__ float errl[256];
  __shared__ float kkl[CSz * Dsz];
  __shared__ float gl[CSz], el[CSz], tl[CSz];
  int bh, eb;
  xcd_decode(blockIdx.x, bh, eb);
  const int b = bh >> 4, h = bh & 15;
  const int tid = threadIdx.x;
  Ml[tid & 255] = Mst[(size_t)bh * 4096 + eb * 4 * 64 + tid];
#pragma unroll
  for (int i = 0; i < 16; ++i) {
    int idx = i * 256 + tid;
    int t = idx >> 6, k = idx & 63;
    kkl[idx] = kp[(((size_t)b * Tsz + ci * CSz + t) * Hsz + h) * Dsz + k];
  }
  if (tid < CSz) {
    size_t gi = ((size_t)b * Tsz + ci * CSz + tid) * Hsz + h;
    gl[tid] = ggamma[gi];
    el[tid] = geta[gi];
    tl[tid] = gtheta[gi];
  }
  __syncthreads();
  {
    const int tt = tid >> 2, vl = tid & 3;
    float acc = 0.f;
#pragma unroll
    for (int i = 0; i < 16; ++i) {
      float4 m4 = *(const float4*)&Ml[vl * 64 + i * 4];
      float4 k4 = *(const float4*)&kkl[tt * 64 + i * 4];
      acc += m4.x * k4.x + m4.y * k4.y + m4.z * k4.z + m4.w * k4.w;
    }
    float vv = vp[(((size_t)b * Tsz + ci * CSz + tt) * Hsz + h) * Dsz + eb * 4 + vl];
    errl[tt * 4 + vl] = acc - vv;
  }
  __syncthreads();
  const int e = eb * 256 + tid;
  const int vloc = tid >> 6;
  const int k = tid & 63;
  float S = Sst[(size_t)bh * 4096 + e];
  float ring[OW];
  float wsum = 0.f;
  float* outp = chunkS + (size_t)bh * CSz * 4096 + e;
#pragma unroll
  for (int t = 0; t < CSz; ++t) {
    float u = 2.f * errl[t * 4 + vloc] * kkl[t * 64 + k];
    float val = gl[t] * u;
    wsum += val;
    if (t >= OW) wsum -= ring[t & (OW - 1)];
    ring[t & (OW - 1)] = val;
    S = tl[t] * S - el[t] * wsum;
    outp[(size_t)t * 4096] = S;
  }
  Sst[(size_t)bh * 4096 + e] = S;
}

// ---------------------------------------------------------------------------
// Fused: memory scan + read (chunk ci), then momentum scan (chunk ci+1).
// XCD-affinity remap keeps this block's chunkS slab on the same XCD L2 that
// the matching pe_mfma blocks wrote. mem phase: 4x unrolled, reg-prefetched
// Xo loads, 4-way-ILP butterfly reductions, stores spread over lanes 0-3.
// ---------------------------------------------------------------------------
__global__ __launch_bounds__(256) void fused_scan_kernel(float* __restrict__ chunkS,
                                                         const float* __restrict__ qp,
                                                         const float* __restrict__ kp,
                                                         const float* __restrict__ vp,
                                                         const float* __restrict__ galpha,
                                                         const float* __restrict__ geta,
                                                         const float* __restrict__ gtheta,
                                                         const float* __restrict__ ggamma,
                                                         float* __restrict__ Mst,
                                                         float* __restrict__ Sst,
                                                         float* __restrict__ ybuf,
                                                         int ci, int do_next) {
  __shared__ float buf[CSz * Dsz];  // ql (mem phase) then kkl (mom phase)
  __shared__ float al[CSz];
  __shared__ float Ml[4 * Dsz];
  __shared__ float errl[256];
  __shared__ float gl[CSz], el[CSz], tl[CSz];
  int bh, eb;
  xcd_decode(blockIdx.x, bh, eb);
  const int b = bh >> 4, h = bh & 15;
  const int tid = threadIdx.x;
  const int w = tid >> 6, lane = tid & 63;
  const int v = eb * 4 + w, k = lane;
  // ---- mem phase (chunk ci) ----
  for (int i = tid; i < CSz * Dsz; i += 256) {
    int t = i >> 6, kk = i & 63;
    buf[i] = qp[(((size_t)b * Tsz + ci * CSz + t) * Hsz + h) * Dsz + kk];
  }
  if (tid < CSz) al[tid] = galpha[((size_t)b * Tsz + ci * CSz + tid) * Hsz + h];
  __syncthreads();
  float m = Mst[(size_t)bh * 4096 + v * 64 + k];
  const float* Xp = chunkS + (size_t)bh * CSz * 4096 + v * 64 + k;
  float* yb = ybuf + (((size_t)b * Tsz + ci * CSz) * Hsz + h) * Dsz + v;
  float x0 = Xp[0], x1 = Xp[4096], x2 = Xp[8192], x3 = Xp[12288];
  for (int t0 = 0; t0 < CSz; t0 += 4) {
    float n0, n1, n2, n3;
    if (t0 + 4 < CSz) {
      const float* Xn = Xp + (size_t)(t0 + 4) * 4096;
      n0 = Xn[0]; n1 = Xn[4096]; n2 = Xn[8192]; n3 = Xn[12288];
    } else {
      n0 = n1 = n2 = n3 = 0.f;
    }
    float m0 = al[t0] * m + x0;
    float m1 = al[t0 + 1] * m0 + x1;
    float m2 = al[t0 + 2] * m1 + x2;
    float m3 = al[t0 + 3] * m2 + x3;
    m = m3;
    float p0 = m0 * buf[(t0 + 0) * 64 + k];
    float p1 = m1 * buf[(t0 + 1) * 64 + k];
    float p2 = m2 * buf[(t0 + 2) * 64 + k];
    float p3 = m3 * buf[(t0 + 3) * 64 + k];
#pragma unroll
    for (int off = 32; off; off >>= 1) {
      p0 += __shfl_xor(p0, off, 64);
      p1 += __shfl_xor(p1, off, 64);
      p2 += __shfl_xor(p2, off, 64);
      p3 += __shfl_xor(p3, off, 64);
    }
    if (lane < 4) {
      float pj = (lane == 0 ? p0 : lane == 1 ? p1 : lane == 2 ? p2 : p3);
      yb[(size_t)(t0 + lane) * Hsz * Dsz] = pj;
    }
    x0 = n0; x1 = n1; x2 = n2; x3 = n3;
  }
  Mst[(size_t)bh * 4096 + v * 64 + k] = m;
  if (!do_next) return;
  Ml[w * 64 + k] = m;
  __syncthreads();  // ql reads done (buf reusable); Ml visible
  // ---- mom phase (chunk ci+1) ----
  const int cj = ci + 1;
#pragma unroll
  for (int i = 0; i < 16; ++i) {
    int idx = i * 256 + tid;
    int t = idx >> 6, kk = idx & 63;
    buf[idx] = kp[(((size_t)b * Tsz + cj * CSz + t) * Hsz + h) * Dsz + kk];
  }
  if (tid < CSz) {
    size_t gi = ((size_t)b * Tsz + cj * CSz + tid) * Hsz + h;
    gl[tid] = ggamma[gi];
    el[tid] = geta[gi];
    tl[tid] = gtheta[gi];
  }
  __syncthreads();
  {
    const int tt = tid >> 2, vl = tid & 3;
    float acc = 0.f;
#pragma unroll
    for (int i = 0; i < 16; ++i) {
      float4 m4 = *(const float4*)&Ml[vl * 64 + i * 4];
      float4 k4 = *(const float4*)&buf[tt * 64 + i * 4];
      acc += m4.x * k4.x + m4.y * k4.y + m4.z * k4.z + m4.w * k4.w;
    }
    float vv = vp[(((size_t)b * Tsz + cj * CSz + tt) * Hsz + h) * Dsz + eb * 4 + vl];
    errl[tt * 4 + vl] = acc - vv;
  }
  __syncthreads();
  const int e = eb * 256 + tid;
  const int vloc = tid >> 6;
  float S = Sst[(size_t)bh * 4096 + e];
  float ring[OW];
  float wsum = 0.f;
  float* outp = chunkS + (size_t)bh * CSz * 4096 + e;
#pragma unroll
  for (int t = 0; t < CSz; ++t) {
    float u = 2.f * errl[t * 4 + vloc] * buf[t * 64 + k];
    float val = gl[t] * u;
    wsum += val;
    if (t >= OW) wsum -= ring[t & (OW - 1)];
    ring[t & (OW - 1)] = val;
    S = tl[t] * S - el[t] * wsum;
    outp[(size_t)t * 4096] = S;
  }
  Sst[(size_t)bh * 4096 + e] = S;
}

// ---------------------------------------------------------------------------
// B3: Polar Express via scaled split-f16 MFMA, re-associated dataflow:
//   A = X X^T ; W = A X ; U = A W ; X' = a X + b W + c U
// blockIdx XCD-remapped so all 64 matrices of a bh stay on XCD bh%8.
// ---------------------------------------------------------------------------
__global__ __launch_bounds__(256, 3) void pe_mfma_kernel(float* __restrict__ chunkS) {
  __shared__ __attribute__((aligned(16))) _Float16 PL[6 * 4096];
  __shared__ float red[4];
  const int tid = threadIdx.x;
  const int lane = tid & 63;
  const int wv = tid >> 6;
  int bh, tmat;
  xcd_decode(blockIdx.x, bh, tmat);
  float* G = chunkS + ((size_t)bh * CSz + tmat) * 4096;
  constexpr int PLO = 8192;   // hi->lo plane byte distance
  constexpr int PT = 16384;   // X^T plane pair (fixed role)
  char* const LB = (char*)PL;

  const int mb = (wv >> 1) << 5;
  const int nb = (wv & 1) << 5;
  const int crow = ((lane >> 5) << 2);
  const int ccol = lane & 31;

  int ra_m[4], ra_n[4];
#pragma unroll
  for (int ks = 0; ks < 4; ++ks) {
    int rm = mb + (lane & 31), rn = nb + (lane & 31);
    int cB = (ks << 5) + ((lane >> 5) << 4);
    ra_m[ks] = (rm << 7) + (cB ^ ((rm & 7) << 4));
    ra_n[ks] = (rn << 7) + (cB ^ ((rn & 7) << 4));
  }
  int sa[4];
  {
    const int base = (nb + ccol) << 7;
    const int sw = ((nb + ccol) & 7) << 4;
    const int c2 = crow << 1;
#pragma unroll
    for (int g = 0; g < 4; ++g) sa[g] = base + ((((mb + 8 * g) << 1) ^ sw) + c2);
  }
  int rowa[4];
#pragma unroll
  for (int j = 0; j < 4; ++j) {
    int rr = mb + crow + j;
    rowa[j] = (rr << 7) + (((nb + ccol) << 1) ^ ((rr & 7) << 4));
  }

#define LDF(PB, RA, ks) (*(const half8*)(LB + (PB) + (RA)[ks]))

  auto STS = [&](int PB, const _Float16* hs, const _Float16* ls) {
#pragma unroll
    for (int g = 0; g < 4; ++g) {
      half4 hv, lv;
#pragma unroll
      for (int j = 0; j < 4; ++j) { hv[j] = hs[g * 4 + j]; lv[j] = ls[g * 4 + j]; }
      *(half4*)(LB + PB + sa[g]) = hv;
      *(half4*)(LB + PB + PLO + sa[g]) = lv;
    }
  };
  auto STR = [&](int PB, const _Float16* hs, const _Float16* ls) {
#pragma unroll
    for (int r = 0; r < 16; ++r) {
      int off = rowa[r & 3] + ((r >> 2) << 10);
      *(_Float16*)(LB + PB + off) = hs[r];
      *(_Float16*)(LB + PB + PLO + off) = ls[r];
    }
  };

  float Xval[16];
  float ss = 0.f;
#pragma unroll
  for (int r = 0; r < 16; ++r) {
    int rr = mb + crow + (r & 3) + ((r >> 2) << 3);
    float xv = G[rr * 64 + nb + ccol];
    Xval[r] = xv;
    ss += xv * xv;
  }
#pragma unroll
  for (int off = 32; off; off >>= 1) ss += __shfl_xor(ss, off, 64);
  if (lane == 0) red[wv] = ss;
  __syncthreads();
  float tot = red[0] + red[1] + red[2] + red[3];
  float scale = 1.f / ((sqrtf(tot) + 1e-7f) * 1.01f);

  {
    _Float16 hs[16], ls[16];
#pragma unroll
    for (int r = 0; r < 16; ++r) {
      Xval[r] *= scale;
      split_f16(Xval[r], hs[r], ls[r]);
    }
    STR(0, hs, ls);
    STS(PT, hs, ls);
  }

  auto iter = [&](float ca, float cb, float cc, int PXB, int PAB, bool last) {
    __syncthreads();  // B_a
    if (wv != 2) {
      f32x16 accH, accL;
#pragma unroll
      for (int r = 0; r < 16; ++r) { accH[r] = 0.f; accL[r] = 0.f; }
      __builtin_amdgcn_s_setprio(1);
#pragma unroll
      for (int ks = 0; ks < 4; ++ks) {
        half8 ah = LDF(PXB, ra_m, ks), al = LDF(PXB + PLO, ra_m, ks);
        half8 bh, bl;
        if (mb != nb) { bh = LDF(PXB, ra_n, ks); bl = LDF(PXB + PLO, ra_n, ks); }
        else { bh = ah; bl = al; }
        MFMA2(accH, accL, ah, al, bh, bl);
      }
      __builtin_amdgcn_s_setprio(0);
      _Float16 hs[16], ls[16];
#pragma unroll
      for (int r = 0; r < 16; ++r) split_f16(accH[r] + accL[r] * INV_S, hs[r], ls[r]);
      STS(PAB, hs, ls);
      if (wv == 1) STR(PAB, hs, ls);
    }
    __syncthreads();  // B_b
    half8 fah[4], fal[4];
    f32x16 acWH, acWL;
#pragma unroll
    for (int r = 0; r < 16; ++r) { acWH[r] = 0.f; acWL[r] = 0.f; }
    __builtin_amdgcn_s_setprio(1);
#pragma unroll
    for (int ks = 0; ks < 4; ++ks) {
      fah[ks] = LDF(PAB, ra_m, ks);
      fal[ks] = LDF(PAB + PLO, ra_m, ks);
      half8 bh = LDF(PT, ra_n, ks), bl = LDF(PT + PLO, ra_n, ks);
      MFMA2(acWH, acWL, fah[ks], fal[ks], bh, bl);
    }
    __builtin_amdgcn_s_setprio(0);
    float Wval[16];
    {
      _Float16 hs[16], ls[16];
#pragma unroll
      for (int r = 0; r < 16; ++r) {
        Wval[r] = acWH[r] + acWL[r] * INV_S;
        split_f16(Wval[r], hs[r], ls[r]);
      }
      STS(PXB, hs, ls);
    }
    __syncthreads();  // B_c
    f32x16 acUH, acUL;
#pragma unroll
    for (int r = 0; r < 16; ++r) { acUH[r] = 0.f; acUL[r] = 0.f; }
    __builtin_amdgcn_s_setprio(1);
#pragma unroll
    for (int ks = 0; ks < 4; ++ks) {
      half8 bh = LDF(PXB, ra_n, ks), bl = LDF(PXB + PLO, ra_n, ks);
      MFMA2(acUH, acUL, fah[ks], fal[ks], bh, bl);
    }
    __builtin_amdgcn_s_setprio(0);
    if (!last) {
      _Float16 hs[16], ls[16];
#pragma unroll
      for (int r = 0; r < 16; ++r) {
        float xn = ca * Xval[r] + cb * Wval[r] + cc * (acUH[r] + acUL[r] * INV_S);
        Xval[r] = xn;
        split_f16(xn, hs[r], ls[r]);
      }
      STR(PAB, hs, ls);
      STS(PT, hs, ls);
    } else {
#pragma unroll
      for (int r = 0; r < 16; ++r) {
        int rr = mb + crow + (r & 3) + ((r >> 2) << 3);
        G[rr * 64 + nb + ccol] = ca * Xval[r] + cb * Wval[r] + cc * (acUH[r] + acUL[r] * INV_S);
      }
    }
  };

  iter(8.28721201814563f, -23.595886519098837f, 17.300387312530933f, 0, 32768, false);
  iter(4.107059111542203f, -2.9478499167379106f, 0.5448431082926601f, 32768, 0, false);
  iter(3.9486908534822946f, -2.908902115962949f, 0.5518191394370137f, 0, 32768, false);
  iter(3.3184196573706015f, -2.488488024314874f, 0.51004894012372f, 32768, 0, false);
  iter(2.300652019954817f, -1.6689039845747493f, 0.4188073119525673f, 0, 32768, true);
}

// ---------------------------------------------------------------------------
extern "C" void kernel_launch(void* const* d_in, const int* in_sizes, int n_in,
                              void* d_out, int out_size, void* d_ws, size_t ws_size,
                              hipStream_t stream) {
  (void)in_sizes; (void)n_in; (void)out_size; (void)ws_size;
  const float* x   = (const float*)d_in[0];
  const float* Wq  = (const float*)d_in[1];
  const float* Wk  = (const float*)d_in[2];
  const float* Wv  = (const float*)d_in[3];
  const float* Wo  = (const float*)d_in[4];
  const float* cqw = (const float*)d_in[5];
  const float* cqb = (const float*)d_in[6];
  const float* ckw = (const float*)d_in[7];
  const float* ckb = (const float*)d_in[8];
  const float* cvw = (const float*)d_in[9];
  const float* cvb = (const float*)d_in[10];
  const float* Wa  = (const float*)d_in[11];
  const float* We  = (const float*)d_in[12];
  const float* Wt  = (const float*)d_in[13];
  const float* Wg  = (const float*)d_in[14];
  float* out = (float*)d_out;

  float* p = (float*)d_ws;
  const size_t NBTC = (size_t)Bsz * Tsz * Csz;   // 1M
  const size_t NBTH = (size_t)Bsz * Tsz * Hsz;
  const size_t NMAT = (size_t)Bsz * Hsz * Dsz * Dsz;
  const size_t NWW = (size_t)Csz * Csz;          // 1M
  float* qlin = p; p += NBTC;
  float* klin = p; p += NBTC;
  float* vlin = p; p += NBTC;
  float* qp   = p; p += NBTC;
  float* kp   = p; p += NBTC;
  float* vp   = p; p += NBTC;
  float* ga   = p; p += NBTH;
  float* ge   = p; p += NBTH;
  float* gt   = p; p += NBTH;
  float* gg   = p; p += NBTH;
  float* Mst  = p; p += NMAT;
  float* Sst  = p; p += NMAT;
  float* chS  = p; p += (size_t)Bsz * Hsz * CSz * Dsz * Dsz;
  float* ybuf = p; p += NBTC;
  // f16 split planes
  _Float16* hp = (_Float16*)p;
  _Float16* xh  = hp; hp += NBTC;
  _Float16* xl  = hp; hp += NBTC;
  _Float16* Wqh = hp; hp += NWW;
  _Float16* Wql = hp; hp += NWW;
  _Float16* Wkh = hp; hp += NWW;
  _Float16* Wkl = hp; hp += NWW;
  _Float16* Wvh = hp; hp += NWW;
  _Float16* Wvl = hp; hp += NWW;
  _Float16* Woh = hp; hp += NWW;
  _Float16* Wol = hp; hp += NWW;
  _Float16* gWh = hp; hp += (size_t)64 * Csz;
  _Float16* gWl = hp; hp += (size_t)64 * Csz;
  _Float16* yh  = hp; hp += NBTC;
  _Float16* yl  = hp; hp += NBTC;

  hipMemsetAsync(Mst, 0, NMAT * sizeof(float), stream);
  hipMemsetAsync(Sst, 0, NMAT * sizeof(float), stream);

  split_all_kernel<<<dim3(1024, 6), 256, 0, stream>>>(
      x, Wq, Wk, Wv, Wo, Wa, We, Wt, Wg,
      xh, xl, Wqh, Wql, Wkh, Wkl, Wvh, Wvl, Woh, Wol, gWh, gWl);
  qkvg_mfma<<<dim3(16, 49), 256, 0, stream>>>(
      xh, xl, Wqh, Wql, Wkh, Wkl, Wvh, Wvl, gWh, gWl,
      qlin, klin, vlin, ga, ge, gt, gg);
  conv3_kernel<<<dim3(Bsz * Tsz, 3), 256, 0, stream>>>(qlin, klin, vlin, cqw, ckw, cvw,
                                                       cqb, ckb, cvb, qp, kp, vp);

  mom_scan_kernel<<<Bsz * Hsz * 16, 256, 0, stream>>>(Mst, kp, vp, ge, gt, gg, Sst, chS, 0);
  for (int ci = 0; ci < NCHUNK; ++ci) {
    pe_mfma_kernel<<<Bsz * Hsz * CSz, 256, 0, stream>>>(chS);
    fused_scan_kernel<<<Bsz * Hsz * 16, 256, 0, stream>>>(chS, qp, kp, vp, ga, ge, gt, gg,
                                                          Mst, Sst, ybuf, ci,
                                                          ci < NCHUNK - 1 ? 1 : 0);
  }

  rms_split_kernel<<<Bsz * Tsz, 256, 0, stream>>>(ybuf, yh, yl);
  out_mfma<<<dim3(16, 16), 256, 0, stream>>>(yh, yl, Woh, Wol, out);
}

// Round 7
// 843.555 us; speedup vs baseline: 1.5092x; 1.0335x over previous
//
#include <hip/hip_runtime.h>

// Problem constants
constexpr int Bsz = 2, Tsz = 512, Csz = 1024, Hsz = 16, Dsz = 64, CSz = 64;
constexpr int NCHUNK = 8, OW = 8;

typedef __attribute__((ext_vector_type(8))) _Float16 half8;
typedef __attribute__((ext_vector_type(4))) _Float16 half4;
typedef __attribute__((ext_vector_type(2))) _Float16 half2v;
typedef __attribute__((ext_vector_type(2))) __fp16 fp16x2;
typedef __attribute__((ext_vector_type(16))) float f32x16;

constexpr float INV_S = 1.0f / 2048.0f;

union H4u { half4 v; half2v p[2]; };

// fp32 v ~= hi + lo/2048 (f16 pair). Proven precision-adequate by pe kernel.
__device__ __forceinline__ void split_f16(float v, _Float16& hi, _Float16& lo) {
  _Float16 h = (_Float16)v;
  float r = v - (float)h;
  hi = h;
  lo = (_Float16)(r * 2048.0f);
}

// Packed 2-value split via v_cvt_pkrtz_f16_f32. RTZ on hi is pair-safe:
// residual is captured exactly in lo; pair accuracy limited by lo's own
// rounding (~2^-21 relative) exactly as with RN.
__device__ __forceinline__ void split2(float a, float b, half2v& h, half2v& l) {
  fp16x2 hh = __builtin_amdgcn_cvt_pkrtz(a, b);
  half2v hv = __builtin_bit_cast(half2v, hh);
  float ra = (a - (float)hv[0]) * 2048.0f;
  float rb = (b - (float)hv[1]) * 2048.0f;
  h = hv;
  l = __builtin_bit_cast(half2v, __builtin_amdgcn_cvt_pkrtz(ra, rb));
}

// 3-MFMA split product with accL chain split in two (halves dependent-MFMA
// chain depth; combined in epilogue).
#define MFMA3(accH, accL1, accL2, ah, al, bh, bl)                             \
  accH = __builtin_amdgcn_mfma_f32_32x32x16_f16(ah, bh, accH, 0, 0, 0);       \
  accL1 = __builtin_amdgcn_mfma_f32_32x32x16_f16(ah, bl, accL1, 0, 0, 0);     \
  accL2 = __builtin_amdgcn_mfma_f32_32x32x16_f16(al, bh, accL2, 0, 0, 0);

// XCD-affinity decode: launched bid -> (bh, idx) with XCD(bid)=bid%8 == bh%8.
__device__ __forceinline__ void xcd_decode(int bid, int& bh, int& idx) {
  bh = (((bid >> 3) & 3) << 3) + (bid & 7);
  idx = bid >> 5;
}

// ---------------------------------------------------------------------------
// One-time fp32 -> (hi,lo) f16 plane conversion.
// ---------------------------------------------------------------------------
__global__ __launch_bounds__(256) void split_all_kernel(
    const float* __restrict__ x, const float* __restrict__ Wq,
    const float* __restrict__ Wk, const float* __restrict__ Wv,
    const float* __restrict__ Wo, const float* __restrict__ Wa,
    const float* __restrict__ We, const float* __restrict__ Wt,
    const float* __restrict__ Wg,
    _Float16* __restrict__ xh, _Float16* __restrict__ xl,
    _Float16* __restrict__ Wqh, _Float16* __restrict__ Wql,
    _Float16* __restrict__ Wkh, _Float16* __restrict__ Wkl,
    _Float16* __restrict__ Wvh, _Float16* __restrict__ Wvl,
    _Float16* __restrict__ Woh, _Float16* __restrict__ Wol,
    _Float16* __restrict__ gWh, _Float16* __restrict__ gWl) {
  const int y = blockIdx.y;
  const int tid = threadIdx.x;
  if (y < 5) {
    const float* src = (y == 0 ? x : y == 1 ? Wq : y == 2 ? Wk : y == 3 ? Wv : Wo);
    _Float16* dh = (y == 0 ? xh : y == 1 ? Wqh : y == 2 ? Wkh : y == 3 ? Wvh : Woh);
    _Float16* dl = (y == 0 ? xl : y == 1 ? Wql : y == 2 ? Wkl : y == 3 ? Wvl : Wol);
    size_t i = ((size_t)blockIdx.x * 256 + tid) * 4;
    float4 v = *(const float4*)(src + i);
    H4u h, l;
    split2(v.x, v.y, h.p[0], l.p[0]);
    split2(v.z, v.w, h.p[1], l.p[1]);
    *(half4*)(dh + i) = h.v;
    *(half4*)(dl + i) = l.v;
  } else {
    if (blockIdx.x >= 64) return;
    size_t i = ((size_t)blockIdx.x * 256 + tid) * 4;
    int gsel = (int)(i >> 14);
    int off = (int)(i & 16383);
    const float* src = (gsel == 0 ? Wa : gsel == 1 ? We : gsel == 2 ? Wt : Wg);
    float4 v = *(const float4*)(src + off);
    H4u h, l;
    split2(v.x, v.y, h.p[0], l.p[0]);
    split2(v.z, v.w, h.p[1], l.p[1]);
    *(half4*)(gWh + i) = h.v;
    *(half4*)(gWl + i) = l.v;
  }
}

// ---------------------------------------------------------------------------
// Split-f16 MFMA GEMM core: 64x64 output tile, K=1024, O = A @ B^T.
// ---------------------------------------------------------------------------
__device__ __forceinline__ void gemm64_core(const _Float16* __restrict__ Agh,
                                            const _Float16* __restrict__ Agl,
                                            const _Float16* __restrict__ Bgh,
                                            const _Float16* __restrict__ Bgl,
                                            int m0, int n0, int tid, char* LB,
                                            f32x16& accH, f32x16& accL1, f32x16& accL2) {
  const int lane = tid & 63, wv = tid >> 6;
  const int mb = (wv >> 1) << 5, nb = (wv & 1) << 5;
  const int lr = tid >> 2;             // staging row 0..63
  const int lch = (tid & 3) << 4;      // half col {0,16,32,48}
  const int cb = lch << 1;             // byte col
  const int wb0 = (lr << 7) + (cb ^ ((lr & 7) << 4));
  const int wb1 = (lr << 7) + ((cb + 16) ^ ((lr & 7) << 4));
  const _Float16* pah = Agh + (size_t)(m0 + lr) * Csz + lch;
  const _Float16* pal = Agl + (size_t)(m0 + lr) * Csz + lch;
  const _Float16* pbh = Bgh + (size_t)(n0 + lr) * Csz + lch;
  const _Float16* pbl = Bgl + (size_t)(n0 + lr) * Csz + lch;
  int ra_m[4], ra_n[4];
#pragma unroll
  for (int ks = 0; ks < 4; ++ks) {
    int rm = mb + (lane & 31), rn = nb + (lane & 31);
    int cB = (ks << 5) + ((lane >> 5) << 4);
    ra_m[ks] = (rm << 7) + (cB ^ ((rm & 7) << 4));
    ra_n[ks] = (rn << 7) + (cB ^ ((rn & 7) << 4));
  }
#pragma unroll
  for (int r = 0; r < 16; ++r) { accH[r] = 0.f; accL1[r] = 0.f; accL2[r] = 0.f; }
  for (int k0 = 0; k0 < Csz; k0 += 64) {
    half8 vah0 = *(const half8*)(pah + k0), vah1 = *(const half8*)(pah + k0 + 8);
    half8 val0 = *(const half8*)(pal + k0), val1 = *(const half8*)(pal + k0 + 8);
    half8 vbh0 = *(const half8*)(pbh + k0), vbh1 = *(const half8*)(pbh + k0 + 8);
    half8 vbl0 = *(const half8*)(pbl + k0), vbl1 = *(const half8*)(pbl + k0 + 8);
    __syncthreads();
    *(half8*)(LB + wb0) = vah0;          *(half8*)(LB + wb1) = vah1;
    *(half8*)(LB + 8192 + wb0) = val0;   *(half8*)(LB + 8192 + wb1) = val1;
    *(half8*)(LB + 16384 + wb0) = vbh0;  *(half8*)(LB + 16384 + wb1) = vbh1;
    *(half8*)(LB + 24576 + wb0) = vbl0;  *(half8*)(LB + 24576 + wb1) = vbl1;
    __syncthreads();
    __builtin_amdgcn_s_setprio(1);
#pragma unroll
    for (int ks = 0; ks < 4; ++ks) {
      half8 ah = *(const half8*)(LB + ra_m[ks]);
      half8 al = *(const half8*)(LB + 8192 + ra_m[ks]);
      half8 bh = *(const half8*)(LB + 16384 + ra_n[ks]);
      half8 bl = *(const half8*)(LB + 24576 + ra_n[ks]);
      MFMA3(accH, accL1, accL2, ah, al, bh, bl);
    }
    __builtin_amdgcn_s_setprio(0);
  }
}

// ---------------------------------------------------------------------------
// Fused QKV + gates GEMM via split-f16 MFMA. Grid (16, 49).
// ---------------------------------------------------------------------------
__global__ __launch_bounds__(256) void qkvg_mfma(
    const _Float16* __restrict__ xh, const _Float16* __restrict__ xl,
    const _Float16* __restrict__ Wqh, const _Float16* __restrict__ Wql,
    const _Float16* __restrict__ Wkh, const _Float16* __restrict__ Wkl,
    const _Float16* __restrict__ Wvh, const _Float16* __restrict__ Wvl,
    const _Float16* __restrict__ gWh, const _Float16* __restrict__ gWl,
    float* __restrict__ qlin, float* __restrict__ klin, float* __restrict__ vlin,
    float* __restrict__ ga, float* __restrict__ ge,
    float* __restrict__ gt, float* __restrict__ gg) {
  __shared__ __attribute__((aligned(16))) char LB[32768];
  const int tid = threadIdx.x;
  const int by = blockIdx.y;
  const int m0 = blockIdx.x << 6;
  const _Float16 *Bh, *Bl;
  int n0;
  if (by < 48) {
    const int mat = by >> 4;
    n0 = (by & 15) << 6;
    Bh = (mat == 0 ? Wqh : mat == 1 ? Wkh : Wvh);
    Bl = (mat == 0 ? Wql : mat == 1 ? Wkl : Wvl);
  } else {
    n0 = 0;
    Bh = gWh;
    Bl = gWl;
  }
  f32x16 accH, accL1, accL2;
  gemm64_core(xh, xl, Bh, Bl, m0, n0, tid, LB, accH, accL1, accL2);
  const int lane = tid & 63, wv = tid >> 6;
  const int mb = (wv >> 1) << 5, nb = (wv & 1) << 5;
  const int crow = (lane >> 5) << 2, ccol = lane & 31;
  if (by < 48) {
    const int mat = by >> 4;
    float* O = (mat == 0 ? qlin : mat == 1 ? klin : vlin);
#pragma unroll
    for (int r = 0; r < 16; ++r) {
      int row = mb + crow + (r & 3) + ((r >> 2) << 3);
      O[(size_t)(m0 + row) * Csz + n0 + nb + ccol] = accH[r] + (accL1[r] + accL2[r]) * INV_S;
    }
  } else {
    const int col = nb + ccol;
    const int gsel = col >> 4, h = col & 15;
    float* outp = (gsel == 0 ? ga : gsel == 1 ? ge : gsel == 2 ? gt : gg);
#pragma unroll
    for (int r = 0; r < 16; ++r) {
      int row = mb + crow + (r & 3) + ((r >> 2) << 3);
      float v = accH[r] + (accL1[r] + accL2[r]) * INV_S;
      outp[(size_t)(m0 + row) * Hsz + h] = 1.f / (1.f + expf(-v));
    }
  }
}

// ---------------------------------------------------------------------------
// Out-projection GEMM via split-f16 MFMA. Grid (16,16).
// ---------------------------------------------------------------------------
__global__ __launch_bounds__(256) void out_mfma(
    const _Float16* __restrict__ yh, const _Float16* __restrict__ yl,
    const _Float16* __restrict__ Woh, const _Float16* __restrict__ Wol,
    float* __restrict__ out) {
  __shared__ __attribute__((aligned(16))) char LB[32768];
  const int tid = threadIdx.x;
  const int m0 = blockIdx.x << 6, n0 = blockIdx.y << 6;
  f32x16 accH, accL1, accL2;
  gemm64_core(yh, yl, Woh, Wol, m0, n0, tid, LB, accH, accL1, accL2);
  const int lane = tid & 63, wv = tid >> 6;
  const int mb = (wv >> 1) << 5, nb = (wv & 1) << 5;
  const int crow = (lane >> 5) << 2, ccol = lane & 31;
#pragma unroll
  for (int r = 0; r < 16; ++r) {
    int row = mb + crow + (r & 3) + ((r >> 2) << 3);
    out[(size_t)(m0 + row) * Csz + n0 + nb + ccol] = accH[r] + (accL1[r] + accL2[r]) * INV_S;
  }
}

// ---------------------------------------------------------------------------
// Causal depthwise conv (K=4) + optional rms_norm/poly. Grid (B*T, 3).
// ---------------------------------------------------------------------------
__global__ __launch_bounds__(256) void conv3_kernel(const float* __restrict__ qlin,
                                                    const float* __restrict__ klin,
                                                    const float* __restrict__ vlin,
                                                    const float* __restrict__ cqw,
                                                    const float* __restrict__ ckw,
                                                    const float* __restrict__ cvw,
                                                    const float* __restrict__ cqb,
                                                    const float* __restrict__ ckb,
                                                    const float* __restrict__ cvb,
                                                    float* __restrict__ qp,
                                                    float* __restrict__ kp,
                                                    float* __restrict__ vp) {
  const int sel = blockIdx.y;
  const float* lin = (sel == 0 ? qlin : sel == 1 ? klin : vlin);
  const float* w = (sel == 0 ? cqw : sel == 1 ? ckw : cvw);
  const float* bias = (sel == 0 ? cqb : sel == 1 ? ckb : cvb);
  float* out = (sel == 0 ? qp : sel == 1 ? kp : vp);
  const int do_norm = (sel < 2);
  const int bt = blockIdx.x;
  const int b = bt >> 9, t = bt & 511;
  const int tid = threadIdx.x;
  const int c0 = tid << 2;
  float4 bv = *(const float4*)&bias[c0];
  float v0 = bv.x, v1 = bv.y, v2 = bv.z, v3 = bv.w;
  float4 w0 = *(const float4*)&w[(c0 + 0) * 4];
  float4 w1 = *(const float4*)&w[(c0 + 1) * 4];
  float4 w2 = *(const float4*)&w[(c0 + 2) * 4];
  float4 w3 = *(const float4*)&w[(c0 + 3) * 4];
  const float* base = lin + (size_t)b * Tsz * Csz + c0;
#pragma unroll
  for (int j = 0; j < 4; ++j) {
    int tt = t - 3 + j;
    if (tt < 0) continue;
    float4 xv = *(const float4*)(base + (size_t)tt * Csz);
    v0 += xv.x * (&w0.x)[j];
    v1 += xv.y * (&w1.x)[j];
    v2 += xv.z * (&w2.x)[j];
    v3 += xv.w * (&w3.x)[j];
  }
  if (do_norm) {
    float ss = v0 * v0 + v1 * v1 + v2 * v2 + v3 * v3;
    ss += __shfl_xor(ss, 1, 16);
    ss += __shfl_xor(ss, 2, 16);
    ss += __shfl_xor(ss, 4, 16);
    ss += __shfl_xor(ss, 8, 16);
    float scl = rsqrtf(ss * (1.f / 64.f) + 1e-6f);
    v0 *= scl; v1 *= scl; v2 *= scl; v3 *= scl;
    v0 += 0.5f * v0 * v0; v1 += 0.5f * v1 * v1; v2 += 0.5f * v2 * v2; v3 += 0.5f * v3 * v3;
  }
  float4 o = {v0, v1, v2, v3};
  *(float4*)(out + (size_t)bt * Csz + c0) = o;
}

// ---------------------------------------------------------------------------
// rms_norm for y -> split-f16 planes (feeds out_mfma)
// ---------------------------------------------------------------------------
__global__ __launch_bounds__(256) void rms_split_kernel(const float* __restrict__ in,
                                                        _Float16* __restrict__ yh,
                                                        _Float16* __restrict__ yl) {
  const int bt = blockIdx.x;
  const int tid = threadIdx.x;
  const int c0 = tid << 2;
  float4 xv = *(const float4*)(in + (size_t)bt * Csz + c0);
  float ss = xv.x * xv.x + xv.y * xv.y + xv.z * xv.z + xv.w * xv.w;
  ss += __shfl_xor(ss, 1, 16);
  ss += __shfl_xor(ss, 2, 16);
  ss += __shfl_xor(ss, 4, 16);
  ss += __shfl_xor(ss, 8, 16);
  float scl = rsqrtf(ss * (1.f / 64.f) + 1e-6f);
  H4u h, l;
  split2(xv.x * scl, xv.y * scl, h.p[0], l.p[0]);
  split2(xv.z * scl, xv.w * scl, h.p[1], l.p[1]);
  *(half4*)(yh + (size_t)bt * Csz + c0) = h.v;
  *(half4*)(yl + (size_t)bt * Csz + c0) = l.v;
}

// ---------------------------------------------------------------------------
// Standalone momentum scan (chunk 0 only). XCD-affinity remapped blockIdx.
// ---------------------------------------------------------------------------
__global__ __launch_bounds__(256) void mom_scan_kernel(const float* __restrict__ Mst,
                                                       const float* __restrict__ kp,
                                                       const float* __restrict__ vp,
                                                       const float* __restrict__ geta,
                                                       const float* __restrict__ gtheta,
                                                       const float* __restrict__ ggamma,
                                                       float* __restrict__ Sst,
                                                       float* __restrict__ chunkS, int ci) {
  __shared__ float Ml[4 * Dsz];
  __shared__ float errl[256];
  __shared__ float kkl[CSz * Dsz];
  __shared__ float gl[CSz], el[CSz], tl[CSz];
  int bh, eb;
  xcd_decode(blockIdx.x, bh, eb);
  const int b = bh >> 4, h = bh & 15;
  const int tid = threadIdx.x;
  Ml[tid & 255] = Mst[(size_t)bh * 4096 + eb * 4 * 64 + tid];
#pragma unroll
  for (int i = 0; i < 16; ++i) {
    int idx = i * 256 + tid;
    int t = idx >> 6, k = idx & 63;
    kkl[idx] = kp[(((size_t)b * Tsz + ci * CSz + t) * Hsz + h) * Dsz + k];
  }
  if (tid < CSz) {
    size_t gi = ((size_t)b * Tsz + ci * CSz + tid) * Hsz + h;
    gl[tid] = ggamma[gi];
    el[tid] = geta[gi];
    tl[tid] = gtheta[gi];
  }
  __syncthreads();
  {
    const int tt = tid >> 2, vl = tid & 3;
    float acc = 0.f;
#pragma unroll
    for (int i = 0; i < 16; ++i) {
      float4 m4 = *(const float4*)&Ml[vl * 64 + i * 4];
      float4 k4 = *(const float4*)&kkl[tt * 64 + i * 4];
      acc += m4.x * k4.x + m4.y * k4.y + m4.z * k4.z + m4.w * k4.w;
    }
    float vv = vp[(((size_t)b * Tsz + ci * CSz + tt) * Hsz + h) * Dsz + eb * 4 + vl];
    errl[tt * 4 + vl] = acc - vv;
  }
  __syncthreads();
  const int e = eb * 256 + tid;
  const int vloc = tid >> 6;
  const int k = tid & 63;
  float S = Sst[(size_t)bh * 4096 + e];
  float ring[OW];
  float wsum = 0.f;
  float* outp = chunkS + (size_t)bh * CSz * 4096 + e;
#pragma unroll
  for (int t = 0; t < CSz; ++t) {
    float u = 2.f * errl[t * 4 + vloc] * kkl[t * 64 + k];
    float val = gl[t] * u;
    wsum += val;
    if (t >= OW) wsum -= ring[t & (OW - 1)];
    ring[t & (OW - 1)] = val;
    S = tl[t] * S - el[t] * wsum;
    outp[(size_t)t * 4096] = S;
  }
  Sst[(size_t)bh * 4096 + e] = S;
}

// ---------------------------------------------------------------------------
// Fused: memory scan + read (chunk ci), then momentum scan (chunk ci+1).
// ---------------------------------------------------------------------------
__global__ __launch_bounds__(256) void fused_scan_kernel(float* __restrict__ chunkS,
                                                         const float* __restrict__ qp,
                                                         const float* __restrict__ kp,
                                                         const float* __restrict__ vp,
                                                         const float* __restrict__ galpha,
                                                         const float* __restrict__ geta,
                                                         const float* __restrict__ gtheta,
                                                         const float* __restrict__ ggamma,
                                                         float* __restrict__ Mst,
                                                         float* __restrict__ Sst,
                                                         float* __restrict__ ybuf,
                                                         int ci, int do_next) {
  __shared__ float buf[CSz * Dsz];  // ql (mem phase) then kkl (mom phase)
  __shared__ float al[CSz];
  __shared__ float Ml[4 * Dsz];
  __shared__ float errl[256];
  __shared__ float gl[CSz], el[CSz], tl[CSz];
  int bh, eb;
  xcd_decode(blockIdx.x, bh, eb);
  const int b = bh >> 4, h = bh & 15;
  const int tid = threadIdx.x;
  const int w = tid >> 6, lane = tid & 63;
  const int v = eb * 4 + w, k = lane;
  // ---- mem phase (chunk ci) ----
  for (int i = tid; i < CSz * Dsz; i += 256) {
    int t = i >> 6, kk = i & 63;
    buf[i] = qp[(((size_t)b * Tsz + ci * CSz + t) * Hsz + h) * Dsz + kk];
  }
  if (tid < CSz) al[tid] = galpha[((size_t)b * Tsz + ci * CSz + tid) * Hsz + h];
  __syncthreads();
  float m = Mst[(size_t)bh * 4096 + v * 64 + k];
  const float* Xp = chunkS + (size_t)bh * CSz * 4096 + v * 64 + k;
  float* yb = ybuf + (((size_t)b * Tsz + ci * CSz) * Hsz + h) * Dsz + v;
  float x0 = Xp[0], x1 = Xp[4096], x2 = Xp[8192], x3 = Xp[12288];
  for (int t0 = 0; t0 < CSz; t0 += 4) {
    float n0, n1, n2, n3;
    if (t0 + 4 < CSz) {
      const float* Xn = Xp + (size_t)(t0 + 4) * 4096;
      n0 = Xn[0]; n1 = Xn[4096]; n2 = Xn[8192]; n3 = Xn[12288];
    } else {
      n0 = n1 = n2 = n3 = 0.f;
    }
    float m0 = al[t0] * m + x0;
    float m1 = al[t0 + 1] * m0 + x1;
    float m2 = al[t0 + 2] * m1 + x2;
    float m3 = al[t0 + 3] * m2 + x3;
    m = m3;
    float p0 = m0 * buf[(t0 + 0) * 64 + k];
    float p1 = m1 * buf[(t0 + 1) * 64 + k];
    float p2 = m2 * buf[(t0 + 2) * 64 + k];
    float p3 = m3 * buf[(t0 + 3) * 64 + k];
#pragma unroll
    for (int off = 32; off; off >>= 1) {
      p0 += __shfl_xor(p0, off, 64);
      p1 += __shfl_xor(p1, off, 64);
      p2 += __shfl_xor(p2, off, 64);
      p3 += __shfl_xor(p3, off, 64);
    }
    if (lane < 4) {
      float pj = (lane == 0 ? p0 : lane == 1 ? p1 : lane == 2 ? p2 : p3);
      yb[(size_t)(t0 + lane) * Hsz * Dsz] = pj;
    }
    x0 = n0; x1 = n1; x2 = n2; x3 = n3;
  }
  Mst[(size_t)bh * 4096 + v * 64 + k] = m;
  if (!do_next) return;
  Ml[w * 64 + k] = m;
  __syncthreads();  // ql reads done (buf reusable); Ml visible
  // ---- mom phase (chunk ci+1) ----
  const int cj = ci + 1;
#pragma unroll
  for (int i = 0; i < 16; ++i) {
    int idx = i * 256 + tid;
    int t = idx >> 6, kk = idx & 63;
    buf[idx] = kp[(((size_t)b * Tsz + cj * CSz + t) * Hsz + h) * Dsz + kk];
  }
  if (tid < CSz) {
    size_t gi = ((size_t)b * Tsz + cj * CSz + tid) * Hsz + h;
    gl[tid] = ggamma[gi];
    el[tid] = geta[gi];
    tl[tid] = gtheta[gi];
  }
  __syncthreads();
  {
    const int tt = tid >> 2, vl = tid & 3;
    float acc = 0.f;
#pragma unroll
    for (int i = 0; i < 16; ++i) {
      float4 m4 = *(const float4*)&Ml[vl * 64 + i * 4];
      float4 k4 = *(const float4*)&buf[tt * 64 + i * 4];
      acc += m4.x * k4.x + m4.y * k4.y + m4.z * k4.z + m4.w * k4.w;
    }
    float vv = vp[(((size_t)b * Tsz + cj * CSz + tt) * Hsz + h) * Dsz + eb * 4 + vl];
    errl[tt * 4 + vl] = acc - vv;
  }
  __syncthreads();
  const int e = eb * 256 + tid;
  const int vloc = tid >> 6;
  float S = Sst[(size_t)bh * 4096 + e];
  float ring[OW];
  float wsum = 0.f;
  float* outp = chunkS + (size_t)bh * CSz * 4096 + e;
#pragma unroll
  for (int t = 0; t < CSz; ++t) {
    float u = 2.f * errl[t * 4 + vloc] * buf[t * 64 + k];
    float val = gl[t] * u;
    wsum += val;
    if (t >= OW) wsum -= ring[t & (OW - 1)];
    ring[t & (OW - 1)] = val;
    S = tl[t] * S - el[t] * wsum;
    outp[(size_t)t * 4096] = S;
  }
  Sst[(size_t)bh * 4096 + e] = S;
}

// ---------------------------------------------------------------------------
// B3: Polar Express via scaled split-f16 MFMA, re-associated dataflow:
//   A = X X^T ; W = A X ; U = A W ; X' = a X + b W + c U
// All 4 waves compute stage 1; symmetric STS of each wave's tile covers the
// full A plane (tile (m,n) stored transposed lands at (n,m)).
// ---------------------------------------------------------------------------
__global__ __launch_bounds__(256, 3) void pe_mfma_kernel(float* __restrict__ chunkS) {
  __shared__ __attribute__((aligned(16))) _Float16 PL[6 * 4096];
  __shared__ float red[4];
  const int tid = threadIdx.x;
  const int lane = tid & 63;
  const int wv = tid >> 6;
  int bh, tmat;
  xcd_decode(blockIdx.x, bh, tmat);
  float* G = chunkS + ((size_t)bh * CSz + tmat) * 4096;
  constexpr int PLO = 8192;   // hi->lo plane byte distance
  constexpr int PT = 16384;   // X^T plane pair (fixed role)
  char* const LB = (char*)PL;

  const int mb = (wv >> 1) << 5;
  const int nb = (wv & 1) << 5;
  const int crow = ((lane >> 5) << 2);
  const int ccol = lane & 31;

  int ra_m[4], ra_n[4];
#pragma unroll
  for (int ks = 0; ks < 4; ++ks) {
    int rm = mb + (lane & 31), rn = nb + (lane & 31);
    int cB = (ks << 5) + ((lane >> 5) << 4);
    ra_m[ks] = (rm << 7) + (cB ^ ((rm & 7) << 4));
    ra_n[ks] = (rn << 7) + (cB ^ ((rn & 7) << 4));
  }
  int sa[4];
  {
    const int base = (nb + ccol) << 7;
    const int sw = ((nb + ccol) & 7) << 4;
    const int c2 = crow << 1;
#pragma unroll
    for (int g = 0; g < 4; ++g) sa[g] = base + ((((mb + 8 * g) << 1) ^ sw) + c2);
  }
  int rowa[4];
#pragma unroll
  for (int j = 0; j < 4; ++j) {
    int rr = mb + crow + j;
    rowa[j] = (rr << 7) + (((nb + ccol) << 1) ^ ((rr & 7) << 4));
  }

#define LDF(PB, RA, ks) (*(const half8*)(LB + (PB) + (RA)[ks]))

  // transposed store from packed half2 arrays: plane[col][row] = D[row][col]
  auto STS = [&](int PB, const half2v* h2, const half2v* l2) {
#pragma unroll
    for (int g = 0; g < 4; ++g) {
      H4u hu, lu;
      hu.p[0] = h2[2 * g]; hu.p[1] = h2[2 * g + 1];
      lu.p[0] = l2[2 * g]; lu.p[1] = l2[2 * g + 1];
      *(half4*)(LB + PB + sa[g]) = hu.v;
      *(half4*)(LB + PB + PLO + sa[g]) = lu.v;
    }
  };
  // row store: plane[row][col] = D[row][col]
  auto STR = [&](int PB, const half2v* h2, const half2v* l2) {
#pragma unroll
    for (int r = 0; r < 16; ++r) {
      int off = rowa[r & 3] + ((r >> 2) << 10);
      *(_Float16*)(LB + PB + off) = h2[r >> 1][r & 1];
      *(_Float16*)(LB + PB + PLO + off) = l2[r >> 1][r & 1];
    }
  };

  float Xval[16];
  float ss = 0.f;
#pragma unroll
  for (int r = 0; r < 16; ++r) {
    int rr = mb + crow + (r & 3) + ((r >> 2) << 3);
    float xv = G[rr * 64 + nb + ccol];
    Xval[r] = xv;
    ss += xv * xv;
  }
#pragma unroll
  for (int off = 32; off; off >>= 1) ss += __shfl_xor(ss, off, 64);
  if (lane == 0) red[wv] = ss;
  __syncthreads();
  float tot = red[0] + red[1] + red[2] + red[3];
  float scale = 1.f / ((sqrtf(tot) + 1e-7f) * 1.01f);

  {
    half2v hs2[8], ls2[8];
#pragma unroll
    for (int i = 0; i < 8; ++i) {
      Xval[2 * i] *= scale;
      Xval[2 * i + 1] *= scale;
      split2(Xval[2 * i], Xval[2 * i + 1], hs2[i], ls2[i]);
    }
    STR(0, hs2, ls2);
    STS(PT, hs2, ls2);
  }

  auto iter = [&](float ca, float cb, float cc, int PXB, int PAB, bool last) {
    __syncthreads();  // B_a: X rows + X^T visible; prior stage-3 reads drained
    // ---- stage 1: A = X X^T (all waves; symmetric STS covers full plane) ----
    {
      f32x16 accH, accL1, accL2;
#pragma unroll
      for (int r = 0; r < 16; ++r) { accH[r] = 0.f; accL1[r] = 0.f; accL2[r] = 0.f; }
      __builtin_amdgcn_s_setprio(1);
#pragma unroll
      for (int ks = 0; ks < 4; ++ks) {
        half8 ah = LDF(PXB, ra_m, ks), al = LDF(PXB + PLO, ra_m, ks);
        half8 bh, bl;
        if (mb != nb) { bh = LDF(PXB, ra_n, ks); bl = LDF(PXB + PLO, ra_n, ks); }
        else { bh = ah; bl = al; }
        MFMA3(accH, accL1, accL2, ah, al, bh, bl);
      }
      __builtin_amdgcn_s_setprio(0);
      half2v hs2[8], ls2[8];
#pragma unroll
      for (int i = 0; i < 8; ++i) {
        float a0 = accH[2 * i] + (accL1[2 * i] + accL2[2 * i]) * INV_S;
        float a1 = accH[2 * i + 1] + (accL1[2 * i + 1] + accL2[2 * i + 1]) * INV_S;
        split2(a0, a1, hs2[i], ls2[i]);
      }
      STS(PAB, hs2, ls2);
    }
    __syncthreads();  // B_b: A ready; stage-1 X reads drained -> PX reusable
    // ---- stage 2: W = A X (A-op rows of A kept in regs; B-op rows of X^T) ----
    half8 fah[4], fal[4];
    f32x16 acWH, acWL1, acWL2;
#pragma unroll
    for (int r = 0; r < 16; ++r) { acWH[r] = 0.f; acWL1[r] = 0.f; acWL2[r] = 0.f; }
    __builtin_amdgcn_s_setprio(1);
#pragma unroll
    for (int ks = 0; ks < 4; ++ks) {
      fah[ks] = LDF(PAB, ra_m, ks);
      fal[ks] = LDF(PAB + PLO, ra_m, ks);
      half8 bh = LDF(PT, ra_n, ks), bl = LDF(PT + PLO, ra_n, ks);
      MFMA3(acWH, acWL1, acWL2, fah[ks], fal[ks], bh, bl);
    }
    __builtin_amdgcn_s_setprio(0);
    float Wval[16];
    {
      half2v hs2[8], ls2[8];
#pragma unroll
      for (int i = 0; i < 8; ++i) {
        Wval[2 * i] = acWH[2 * i] + (acWL1[2 * i] + acWL2[2 * i]) * INV_S;
        Wval[2 * i + 1] = acWH[2 * i + 1] + (acWL1[2 * i + 1] + acWL2[2 * i + 1]) * INV_S;
        split2(Wval[2 * i], Wval[2 * i + 1], hs2[i], ls2[i]);
      }
      STS(PXB, hs2, ls2);  // W^T into dead X plane
    }
    __syncthreads();  // B_c: W^T ready; stage-2 PT/PA reads drained
    // ---- stage 3: U = A W (A-op from regs; B-op rows of W^T) ----
    f32x16 acUH, acUL1, acUL2;
#pragma unroll
    for (int r = 0; r < 16; ++r) { acUH[r] = 0.f; acUL1[r] = 0.f; acUL2[r] = 0.f; }
    __builtin_amdgcn_s_setprio(1);
#pragma unroll
    for (int ks = 0; ks < 4; ++ks) {
      half8 bh = LDF(PXB, ra_n, ks), bl = LDF(PXB + PLO, ra_n, ks);
      MFMA3(acUH, acUL1, acUL2, fah[ks], fal[ks], bh, bl);
    }
    __builtin_amdgcn_s_setprio(0);
    if (!last) {
      half2v hs2[8], ls2[8];
#pragma unroll
      for (int i = 0; i < 8; ++i) {
        float u0 = acUH[2 * i] + (acUL1[2 * i] + acUL2[2 * i]) * INV_S;
        float u1 = acUH[2 * i + 1] + (acUL1[2 * i + 1] + acUL2[2 * i + 1]) * INV_S;
        float x0 = ca * Xval[2 * i] + cb * Wval[2 * i] + cc * u0;
        float x1 = ca * Xval[2 * i + 1] + cb * Wval[2 * i + 1] + cc * u1;
        Xval[2 * i] = x0;
        Xval[2 * i + 1] = x1;
        split2(x0, x1, hs2[i], ls2[i]);
      }
      STR(PAB, hs2, ls2);  // X' rows -> dead A plane (next iter's PX)
      STS(PT, hs2, ls2);   // X'^T   -> PT
    } else {
#pragma unroll
      for (int r = 0; r < 16; ++r) {
        int rr = mb + crow + (r & 3) + ((r >> 2) << 3);
        float u = acUH[r] + (acUL1[r] + acUL2[r]) * INV_S;
        G[rr * 64 + nb + ccol] = ca * Xval[r] + cb * Wval[r] + cc * u;
      }
    }
  };

  iter(8.28721201814563f, -23.595886519098837f, 17.300387312530933f, 0, 32768, false);
  iter(4.107059111542203f, -2.9478499167379106f, 0.5448431082926601f, 32768, 0, false);
  iter(3.9486908534822946f, -2.908902115962949f, 0.5518191394370137f, 0, 32768, false);
  iter(3.3184196573706015f, -2.488488024314874f, 0.51004894012372f, 32768, 0, false);
  iter(2.300652019954817f, -1.6689039845747493f, 0.4188073119525673f, 0, 32768, true);
}

// ---------------------------------------------------------------------------
extern "C" void kernel_launch(void* const* d_in, const int* in_sizes, int n_in,
                              void* d_out, int out_size, void* d_ws, size_t ws_size,
                              hipStream_t stream) {
  (void)in_sizes; (void)n_in; (void)out_size; (void)ws_size;
  const float* x   = (const float*)d_in[0];
  const float* Wq  = (const float*)d_in[1];
  const float* Wk  = (const float*)d_in[2];
  const float* Wv  = (const float*)d_in[3];
  const float* Wo  = (const float*)d_in[4];
  const float* cqw = (const float*)d_in[5];
  const float* cqb = (const float*)d_in[6];
  const float* ckw = (const float*)d_in[7];
  const float* ckb = (const float*)d_in[8];
  const float* cvw = (const float*)d_in[9];
  const float* cvb = (const float*)d_in[10];
  const float* Wa  = (const float*)d_in[11];
  const float* We  = (const float*)d_in[12];
  const float* Wt  = (const float*)d_in[13];
  const float* Wg  = (const float*)d_in[14];
  float* out = (float*)d_out;

  float* p = (float*)d_ws;
  const size_t NBTC = (size_t)Bsz * Tsz * Csz;   // 1M
  const size_t NBTH = (size_t)Bsz * Tsz * Hsz;
  const size_t NMAT = (size_t)Bsz * Hsz * Dsz * Dsz;
  const size_t NWW = (size_t)Csz * Csz;          // 1M
  float* qlin = p; p += NBTC;
  float* klin = p; p += NBTC;
  float* vlin = p; p += NBTC;
  float* qp   = p; p += NBTC;
  float* kp   = p; p += NBTC;
  float* vp   = p; p += NBTC;
  float* ga   = p; p += NBTH;
  float* ge   = p; p += NBTH;
  float* gt   = p; p += NBTH;
  float* gg   = p; p += NBTH;
  float* Mst  = p; p += NMAT;
  float* Sst  = p; p += NMAT;
  float* chS  = p; p += (size_t)Bsz * Hsz * CSz * Dsz * Dsz;
  float* ybuf = p; p += NBTC;
  // f16 split planes
  _Float16* hp = (_Float16*)p;
  _Float16* xh  = hp; hp += NBTC;
  _Float16* xl  = hp; hp += NBTC;
  _Float16* Wqh = hp; hp += NWW;
  _Float16* Wql = hp; hp += NWW;
  _Float16* Wkh = hp; hp += NWW;
  _Float16* Wkl = hp; hp += NWW;
  _Float16* Wvh = hp; hp += NWW;
  _Float16* Wvl = hp; hp += NWW;
  _Float16* Woh = hp; hp += NWW;
  _Float16* Wol = hp; hp += NWW;
  _Float16* gWh = hp; hp += (size_t)64 * Csz;
  _Float16* gWl = hp; hp += (size_t)64 * Csz;
  _Float16* yh  = hp; hp += NBTC;
  _Float16* yl  = hp; hp += NBTC;

  hipMemsetAsync(Mst, 0, NMAT * sizeof(float), stream);
  hipMemsetAsync(Sst, 0, NMAT * sizeof(float), stream);

  split_all_kernel<<<dim3(1024, 6), 256, 0, stream>>>(
      x, Wq, Wk, Wv, Wo, Wa, We, Wt, Wg,
      xh, xl, Wqh, Wql, Wkh, Wkl, Wvh, Wvl, Woh, Wol, gWh, gWl);
  qkvg_mfma<<<dim3(16, 49), 256, 0, stream>>>(
      xh, xl, Wqh, Wql, Wkh, Wkl, Wvh, Wvl, gWh, gWl,
      qlin, klin, vlin, ga, ge, gt, gg);
  conv3_kernel<<<dim3(Bsz * Tsz, 3), 256, 0, stream>>>(qlin, klin, vlin, cqw, ckw, cvw,
                                                       cqb, ckb, cvb, qp, kp, vp);

  mom_scan_kernel<<<Bsz * Hsz * 16, 256, 0, stream>>>(Mst, kp, vp, ge, gt, gg, Sst, chS, 0);
  for (int ci = 0; ci < NCHUNK; ++ci) {
    pe_mfma_kernel<<<Bsz * Hsz * CSz, 256, 0, stream>>>(chS);
    fused_scan_kernel<<<Bsz * Hsz * 16, 256, 0, stream>>>(chS, qp, kp, vp, ga, ge, gt, gg,
                                                          Mst, Sst, ybuf, ci,
                                                          ci < NCHUNK - 1 ? 1 : 0);
  }

  rms_split_kernel<<<Bsz * Tsz, 256, 0, stream>>>(ybuf, yh, yl);
  out_mfma<<<dim3(16, 16), 256, 0, stream>>>(yh, yl, Woh, Wol, out);
}